// Round 12
// baseline (296.614 us; speedup 1.0000x reference)
//
#include <hip/hip_runtime.h>
#include <math.h>

#define NN 100000
#define NE 800000
#define D 128

typedef __attribute__((ext_vector_type(8))) short bf16x8;
typedef __attribute__((ext_vector_type(8))) unsigned short u16x8;
typedef __attribute__((ext_vector_type(4))) float f32x4;
typedef __attribute__((ext_vector_type(2))) float f32x2;

// ---- workspace layout (bytes) ----
constexpr size_t OFF_RS  = 0;                         // int[NN+1]
constexpr size_t OFF_CNT = 512 * 1024;                // int[NN] histogram
constexpr size_t OFF_CUR = 1024 * 1024;               // int[NN] cursor -> row_end
constexpr size_t OFF_BS  = 1536 * 1024;               // int[512] block sums
constexpr size_t OFF_WB  = 1552 * 1024;               // bf16 weights (98304 elems)
constexpr size_t OFF_SRC = 2 * 1024 * 1024;           // int[NE]
constexpr size_t OFF_EID = 6 * 1024 * 1024;           // int[NE]
constexpr size_t OFF_B0  = 10 * 1024 * 1024;          // bf16[100096*128] xb -> Vb
constexpr size_t OFF_B2  = OFF_B0 + 26 * 1024 * 1024; // h1b (bf16, root reads)
constexpr size_t OFF_X8  = OFF_B2 + 26 * 1024 * 1024; // fp8 x   [NN*128]
constexpr size_t OFF_H8  = OFF_X8 + 13 * 1024 * 1024; // fp8 h1  [NN*128]
constexpr size_t OFF_U8  = OFF_H8 + 13 * 1024 * 1024; // fp8 U   [NN*128]

__device__ __forceinline__ unsigned short f2b(float f) {
    unsigned u = __builtin_bit_cast(unsigned, f);
    return (unsigned short)((u + 0x7FFFu + ((u >> 16) & 1u)) >> 16);
}
__device__ __forceinline__ float b2f(unsigned short h) {
    unsigned u = ((unsigned)h) << 16;
    return __builtin_bit_cast(float, u);
}

// ------------- fused prep: x->bf16+fp8 | weights->bf16 | degree histogram ---
__global__ __launch_bounds__(256) void k_prep(const float* __restrict__ x,
                                              unsigned short* __restrict__ xb,
                                              unsigned* __restrict__ x8w,
                                              const float* __restrict__ W1l,
                                              const float* __restrict__ W1r,
                                              const float* __restrict__ W2l,
                                              const float* __restrict__ W2r,
                                              const float* __restrict__ Wm1,
                                              unsigned short* __restrict__ wb,
                                              const int* __restrict__ dst,
                                              int* __restrict__ cnt) {
    int bid = blockIdx.x, tid = threadIdx.x;
    if (bid < 12500) {                       // x conversion, float4 granules
        int i = bid * 256 + tid;             // 3,200,000 = NN*D/4 exactly
        float4 v = *(const float4*)&x[(size_t)i * 4];
        ushort4 o;
        o.x = f2b(v.x); o.y = f2b(v.y); o.z = f2b(v.z); o.w = f2b(v.w);
        *(ushort4*)&xb[(size_t)i * 4] = o;
        unsigned p = __builtin_amdgcn_cvt_pk_fp8_f32(v.x, v.y, 0u, false);
        p = __builtin_amdgcn_cvt_pk_fp8_f32(v.z, v.w, p, true);
        x8w[i] = p;
    } else if (bid < 12884) {                // weights: 98304 elems
        int i = (bid - 12500) * 256 + tid;
        float v;
        if (i < 16384) v = W1l[i];
        else if (i < 32768) v = W1r[i - 16384];
        else if (i < 49152) v = W2l[i - 32768];
        else if (i < 65536) v = W2r[i - 49152];
        else v = Wm1[i - 65536];
        wb[i] = f2b(v);
    } else {                                 // degree histogram
        int e = (bid - 12884) * 256 + tid;
        atomicAdd(&cnt[dst[e]], 1);
    }
}

// ---------------- CSR scan chain ----------------
__global__ __launch_bounds__(256) void k_scan1(const int* __restrict__ cnt,
                                               int* __restrict__ bsum) {
    int i = blockIdx.x * 256 + threadIdx.x;
    int v = (i < NN) ? cnt[i] : 0;
    #pragma unroll
    for (int o = 1; o < 64; o <<= 1) v += __shfl_xor(v, o);
    __shared__ int wsum[4];
    if ((threadIdx.x & 63) == 0) wsum[threadIdx.x >> 6] = v;
    __syncthreads();
    if (threadIdx.x == 0) bsum[blockIdx.x] = wsum[0] + wsum[1] + wsum[2] + wsum[3];
}

__global__ __launch_bounds__(512) void k_scan2(int* __restrict__ bsum, int nb) {
    __shared__ int s[512];
    int t = threadIdx.x;
    int v = (t < nb) ? bsum[t] : 0;
    s[t] = v;
    __syncthreads();
    for (int o = 1; o < 512; o <<= 1) {
        int u = (t >= o) ? s[t - o] : 0;
        __syncthreads();
        s[t] += u;
        __syncthreads();
    }
    if (t < nb) bsum[t] = s[t] - v;   // exclusive
}

__global__ __launch_bounds__(256) void k_scan3(const int* __restrict__ cnt,
                                               const int* __restrict__ bsum,
                                               int* __restrict__ rs,
                                               int* __restrict__ cur) {
    __shared__ int s[256];
    int t = threadIdx.x;
    int i = blockIdx.x * 256 + t;
    int v = (i < NN) ? cnt[i] : 0;
    s[t] = v;
    __syncthreads();
    for (int o = 1; o < 256; o <<= 1) {
        int u = (t >= o) ? s[t - o] : 0;
        __syncthreads();
        s[t] += u;
        __syncthreads();
    }
    int ex = s[t] - v + bsum[blockIdx.x];
    if (i < NN) { rs[i] = ex; cur[i] = ex; }
    if (i == NN - 1) rs[NN] = ex + v;
}

__global__ __launch_bounds__(256) void k_scatter_idx(const int* __restrict__ src,
                                                     const int* __restrict__ dst,
                                                     int* __restrict__ cur,
                                                     int* __restrict__ srcs,
                                                     int* __restrict__ eids) {
    int e = blockIdx.x * 256 + threadIdx.x;
    if (e < NE) {
        int pos = atomicAdd(&cur[dst[e]], 1);
        srcs[pos] = src[e];
        eids[pos] = e;
    }
}

// ---- gather-mean (fp8 rows), 8 lanes x 16B per row: 1 row per group -------
// 64 groups per 512-thr block; serial chain = ceil(deg/8) rounds (typ. 1).
#define UNPK16(acc, u) {                                                   \
    f32x2 p;                                                               \
    p = __builtin_amdgcn_cvt_pk_f32_fp8(u.x, false); acc[0]  += p.x; acc[1]  += p.y; \
    p = __builtin_amdgcn_cvt_pk_f32_fp8(u.x, true);  acc[2]  += p.x; acc[3]  += p.y; \
    p = __builtin_amdgcn_cvt_pk_f32_fp8(u.y, false); acc[4]  += p.x; acc[5]  += p.y; \
    p = __builtin_amdgcn_cvt_pk_f32_fp8(u.y, true);  acc[6]  += p.x; acc[7]  += p.y; \
    p = __builtin_amdgcn_cvt_pk_f32_fp8(u.z, false); acc[8]  += p.x; acc[9]  += p.y; \
    p = __builtin_amdgcn_cvt_pk_f32_fp8(u.z, true);  acc[10] += p.x; acc[11] += p.y; \
    p = __builtin_amdgcn_cvt_pk_f32_fp8(u.w, false); acc[12] += p.x; acc[13] += p.y; \
    p = __builtin_amdgcn_cvt_pk_f32_fp8(u.w, true);  acc[14] += p.x; acc[15] += p.y; }

__device__ __forceinline__ void gather_mean64(const unsigned char* __restrict__ feat8,
                                              const int* __restrict__ rs,
                                              const int* __restrict__ re,
                                              const int* __restrict__ srcs,
                                              int n0, unsigned short* agt) {
    const int tid = threadIdx.x;
    const int g = tid >> 3;          // row 0..63: one row per 8-lane group
    const int q = tid & 7;           // 16B chunk
    int n = n0 + g;
    if (n > NN - 1) n = NN - 1;      // tail clamp (NN%64==32)
    int b = rs[n], e = re[n];
    float acc[16] = {};
    int j = b;
    for (; j + 7 < e; j += 8) {
        uint4 v0 = *(const uint4*)&feat8[(size_t)srcs[j]     * 128 + q * 16];
        uint4 v1 = *(const uint4*)&feat8[(size_t)srcs[j + 1] * 128 + q * 16];
        uint4 v2 = *(const uint4*)&feat8[(size_t)srcs[j + 2] * 128 + q * 16];
        uint4 v3 = *(const uint4*)&feat8[(size_t)srcs[j + 3] * 128 + q * 16];
        uint4 v4 = *(const uint4*)&feat8[(size_t)srcs[j + 4] * 128 + q * 16];
        uint4 v5 = *(const uint4*)&feat8[(size_t)srcs[j + 5] * 128 + q * 16];
        uint4 v6 = *(const uint4*)&feat8[(size_t)srcs[j + 6] * 128 + q * 16];
        uint4 v7 = *(const uint4*)&feat8[(size_t)srcs[j + 7] * 128 + q * 16];
        UNPK16(acc, v0); UNPK16(acc, v1); UNPK16(acc, v2); UNPK16(acc, v3);
        UNPK16(acc, v4); UNPK16(acc, v5); UNPK16(acc, v6); UNPK16(acc, v7);
    }
    for (; j + 3 < e; j += 4) {
        uint4 v0 = *(const uint4*)&feat8[(size_t)srcs[j]     * 128 + q * 16];
        uint4 v1 = *(const uint4*)&feat8[(size_t)srcs[j + 1] * 128 + q * 16];
        uint4 v2 = *(const uint4*)&feat8[(size_t)srcs[j + 2] * 128 + q * 16];
        uint4 v3 = *(const uint4*)&feat8[(size_t)srcs[j + 3] * 128 + q * 16];
        UNPK16(acc, v0); UNPK16(acc, v1); UNPK16(acc, v2); UNPK16(acc, v3);
    }
    for (; j < e; ++j) {
        uint4 v0 = *(const uint4*)&feat8[(size_t)srcs[j] * 128 + q * 16];
        UNPK16(acc, v0);
    }
    float inv = 1.0f / fmaxf((float)(e - b), 1.0f);
    u16x8 o0, o1;
    #pragma unroll
    for (int i = 0; i < 8; ++i) {
        o0[i] = f2b(acc[i] * inv);
        o1[i] = f2b(acc[8 + i] * inv);
    }
    *(u16x8*)&agt[g * 136 + q * 16]     = o0;
    *(u16x8*)&agt[g * 136 + q * 16 + 8] = o1;
}

// stage 64 global bf16 rows -> LDS tile [64][136] (coalesced, clamped)
__device__ __forceinline__ void stage_tile(const unsigned short* __restrict__ src,
                                           int n0, unsigned short* t) {
    const int tid = threadIdx.x;
    #pragma unroll
    for (int it = 0; it < 2; ++it) {
        int idx = it * 512 + tid;
        int r = idx >> 4, c = (idx & 15) * 8;
        int gr = n0 + r;
        if (gr > NN - 1) gr = NN - 1;
        *(u16x8*)&t[r * 136 + c] = *(const u16x8*)&src[(size_t)gr * D + c];
    }
}

// store LDS tile [64][136] -> global bf16 (coalesced, guarded)
__device__ __forceinline__ void store_tile(const unsigned short* t,
                                           int n0, unsigned short* __restrict__ dstp) {
    const int tid = threadIdx.x;
    #pragma unroll
    for (int it = 0; it < 2; ++it) {
        int idx = it * 512 + tid;
        int r = idx >> 4, c = (idx & 15) * 8;
        int gr = n0 + r;
        if (gr < NN)
            *(u16x8*)&dstp[(size_t)gr * D + c] = *(const u16x8*)&t[r * 136 + c];
    }
}

// store LDS bf16 tile -> global fp8 (coalesced 4B words, guarded)
__device__ __forceinline__ void store_tile_fp8(const unsigned short* t,
                                               int n0, unsigned char* __restrict__ dst8) {
    const int tid = threadIdx.x;
    #pragma unroll
    for (int it = 0; it < 4; ++it) {
        int w = it * 512 + tid;          // word 0..2047
        int r = w >> 5, c4 = (w & 31) * 4;
        int gr = n0 + r;
        if (gr < NN) {
            unsigned p = __builtin_amdgcn_cvt_pk_fp8_f32(
                b2f(t[r * 136 + c4 + 0]), b2f(t[r * 136 + c4 + 1]), 0u, false);
            p = __builtin_amdgcn_cvt_pk_fp8_f32(
                b2f(t[r * 136 + c4 + 2]), b2f(t[r * 136 + c4 + 3]), p, true);
            *(unsigned*)&dst8[(size_t)gr * 128 + c4] = p;
        }
    }
}

// ---------------- fused agg + conv1: h1 = relu(mean@W1l^T + b + x@W1r^T) ----
__global__ __launch_bounds__(512) void k_aggconv1(const unsigned short* __restrict__ xb,
                                                  const unsigned char* __restrict__ x8,
                                                  const int* __restrict__ rs,
                                                  const int* __restrict__ re,
                                                  const int* __restrict__ srcs,
                                                  const unsigned short* __restrict__ Wlb,
                                                  const unsigned short* __restrict__ Wrb,
                                                  const float* __restrict__ bias,
                                                  unsigned short* __restrict__ hout,
                                                  unsigned char* __restrict__ h8) {
    __shared__ unsigned short agt[64 * 136];
    __shared__ unsigned short sto[64 * 136];
    const int tid = threadIdx.x;
    const int n0 = blockIdx.x * 64;

    stage_tile(xb, n0, sto);
    gather_mean64(x8, rs, re, srcs, n0, agt);
    __syncthreads();

    const int wv = tid >> 6, l = tid & 63;
    const int lrow = l & 15, lk = (l >> 4) * 8;
    f32x4 acc[4] = {};
    #pragma unroll
    for (int p = 0; p < 2; ++p) {
        const unsigned short* W  = p ? Wrb : Wlb;
        const unsigned short* At = p ? sto : agt;
        #pragma unroll
        for (int ks = 0; ks < 4; ++ks) {
            bf16x8 bfr = *(const bf16x8*)&W[(size_t)(wv * 16 + lrow) * D + ks * 32 + lk];
            #pragma unroll
            for (int mt = 0; mt < 4; ++mt) {
                bf16x8 af = *(const bf16x8*)&At[(mt * 16 + lrow) * 136 + ks * 32 + lk];
                acc[mt] = __builtin_amdgcn_mfma_f32_16x16x32_bf16(af, bfr, acc[mt], 0, 0, 0);
            }
        }
    }
    __syncthreads();   // all sto (x-tile) reads done before overwrite
    const int orow = (l >> 4) * 4, ocol = l & 15;
    float bb = bias[wv * 16 + ocol];
    #pragma unroll
    for (int mt = 0; mt < 4; ++mt)
        #pragma unroll
        for (int j = 0; j < 4; ++j)
            sto[(mt * 16 + orow + j) * 136 + wv * 16 + ocol] =
                f2b(fmaxf(acc[mt][j] + bb, 0.0f));
    __syncthreads();
    store_tile(sto, n0, hout);
    store_tile_fp8(sto, n0, h8);
}

// ------- fused agg + conv2 + U/V: h2 in LDS; U -> fp8, V -> bf16 -------
__global__ __launch_bounds__(512) void k_aggconv2uv(const unsigned short* __restrict__ h1b,
                                                    const unsigned char* __restrict__ h8,
                                                    const int* __restrict__ rs,
                                                    const int* __restrict__ re,
                                                    const int* __restrict__ srcs,
                                                    const unsigned short* __restrict__ Wlb,
                                                    const unsigned short* __restrict__ Wrb,
                                                    const float* __restrict__ bias,
                                                    const unsigned short* __restrict__ Wm1b,
                                                    const float* __restrict__ bm1,
                                                    unsigned char* __restrict__ U8,
                                                    unsigned short* __restrict__ Vb) {
    __shared__ unsigned short agt[64 * 136];
    __shared__ unsigned short sto[64 * 136];
    const int tid = threadIdx.x;
    const int n0 = blockIdx.x * 64;

    stage_tile(h1b, n0, sto);                 // h1 tile (root) -> sto
    gather_mean64(h8, rs, re, srcs, n0, agt); // fp8 gather
    __syncthreads();                          // (a)

    const int wv = tid >> 6, l = tid & 63;
    const int lrow = l & 15, lk = (l >> 4) * 8;
    const int orow = (l >> 4) * 4, ocol = l & 15;

    // phase 1: h2 = relu(agg@W2l^T + b + h1@W2r^T)
    f32x4 acc[4] = {};
    #pragma unroll
    for (int p = 0; p < 2; ++p) {
        const unsigned short* W  = p ? Wrb : Wlb;
        const unsigned short* At = p ? sto : agt;
        #pragma unroll
        for (int ks = 0; ks < 4; ++ks) {
            bf16x8 bfr = *(const bf16x8*)&W[(size_t)(wv * 16 + lrow) * D + ks * 32 + lk];
            #pragma unroll
            for (int mt = 0; mt < 4; ++mt) {
                bf16x8 af = *(const bf16x8*)&At[(mt * 16 + lrow) * 136 + ks * 32 + lk];
                acc[mt] = __builtin_amdgcn_mfma_f32_16x16x32_bf16(af, bfr, acc[mt], 0, 0, 0);
            }
        }
    }
    __syncthreads();                          // (b) all agt/sto reads done
    {   // h2 epilogue -> agt
        float bb = bias[wv * 16 + ocol];
        #pragma unroll
        for (int mt = 0; mt < 4; ++mt)
            #pragma unroll
            for (int j = 0; j < 4; ++j)
                agt[(mt * 16 + orow + j) * 136 + wv * 16 + ocol] =
                    f2b(fmaxf(acc[mt][j] + bb, 0.0f));
    }
    __syncthreads();                          // (c) h2 tile complete in agt

    f32x4 aU[4] = {}, aV[4] = {};
    #pragma unroll
    for (int ks = 0; ks < 4; ++ks) {
        bf16x8 bu = *(const bf16x8*)&Wm1b[(size_t)(wv * 16 + lrow) * 256 + ks * 32 + lk];
        bf16x8 bv = *(const bf16x8*)&Wm1b[(size_t)(wv * 16 + lrow) * 256 + 128 + ks * 32 + lk];
        #pragma unroll
        for (int mt = 0; mt < 4; ++mt) {
            bf16x8 af = *(const bf16x8*)&agt[(mt * 16 + lrow) * 136 + ks * 32 + lk];
            aU[mt] = __builtin_amdgcn_mfma_f32_16x16x32_bf16(af, bu, aU[mt], 0, 0, 0);
            aV[mt] = __builtin_amdgcn_mfma_f32_16x16x32_bf16(af, bv, aV[mt], 0, 0, 0);
        }
    }
    {   // stage U -> sto (h1-tile reads ended at (b))
        float bb = bm1[wv * 16 + ocol];
        #pragma unroll
        for (int mt = 0; mt < 4; ++mt)
            #pragma unroll
            for (int j = 0; j < 4; ++j)
                sto[(mt * 16 + orow + j) * 136 + wv * 16 + ocol] = f2b(aU[mt][j] + bb);
    }
    __syncthreads();                          // (d) U staged; all agt (h2) reads done
    store_tile_fp8(sto, n0, U8);              // U only as fp8
    {   // stage V -> agt
        #pragma unroll
        for (int mt = 0; mt < 4; ++mt)
            #pragma unroll
            for (int j = 0; j < 4; ++j)
                agt[(mt * 16 + orow + j) * 136 + wv * 16 + ocol] = f2b(aV[mt][j]);
    }
    __syncthreads();                          // (e)
    store_tile(agt, n0, Vb);
}

// ---------------- edge finalize, dst-grouped (round-10 proven), fp8 U ------
__global__ __launch_bounds__(256) void k_edge2(const unsigned char* __restrict__ U8,
                                               const unsigned short* __restrict__ Vb,
                                               const int* __restrict__ rs,
                                               const int* __restrict__ re,
                                               const int* __restrict__ srcs,
                                               const int* __restrict__ eids,
                                               const float* __restrict__ wm2,
                                               const float* __restrict__ bm2,
                                               float* __restrict__ out) {
    int t = blockIdx.x * 256 + threadIdx.x;
    int g = t >> 4, q = t & 15;
    if (g >= NN) return;
    int b = rs[g], e = re[g];
    if (b == e) return;
    u16x8 vv = *(const u16x8*)&Vb[(size_t)g * D + q * 8];
    float vf[8], wf[8];
    #pragma unroll
    for (int i = 0; i < 8; ++i) vf[i] = b2f(vv[i]);
    float4 w0 = *(const float4*)&wm2[q * 8];
    float4 w1 = *(const float4*)&wm2[q * 8 + 4];
    wf[0] = w0.x; wf[1] = w0.y; wf[2] = w0.z; wf[3] = w0.w;
    wf[4] = w1.x; wf[5] = w1.y; wf[6] = w1.z; wf[7] = w1.w;
    const float bb = bm2[0];

#define EDOT(p, u) {                                                   \
    f32x2 q0 = __builtin_amdgcn_cvt_pk_f32_fp8(u.x, false);            \
    f32x2 q1 = __builtin_amdgcn_cvt_pk_f32_fp8(u.x, true);             \
    f32x2 q2 = __builtin_amdgcn_cvt_pk_f32_fp8(u.y, false);            \
    f32x2 q3 = __builtin_amdgcn_cvt_pk_f32_fp8(u.y, true);             \
    p += fmaxf(q0.x + vf[0], 0.0f) * wf[0] + fmaxf(q0.y + vf[1], 0.0f) * wf[1] \
       + fmaxf(q1.x + vf[2], 0.0f) * wf[2] + fmaxf(q1.y + vf[3], 0.0f) * wf[3] \
       + fmaxf(q2.x + vf[4], 0.0f) * wf[4] + fmaxf(q2.y + vf[5], 0.0f) * wf[5] \
       + fmaxf(q3.x + vf[6], 0.0f) * wf[6] + fmaxf(q3.y + vf[7], 0.0f) * wf[7]; }

    int j = b;
    for (; j + 7 < e; j += 8) {
        uint2 u0 = *(const uint2*)&U8[(size_t)srcs[j]     * 128 + q * 8];
        uint2 u1 = *(const uint2*)&U8[(size_t)srcs[j + 1] * 128 + q * 8];
        uint2 u2 = *(const uint2*)&U8[(size_t)srcs[j + 2] * 128 + q * 8];
        uint2 u3 = *(const uint2*)&U8[(size_t)srcs[j + 3] * 128 + q * 8];
        uint2 u4 = *(const uint2*)&U8[(size_t)srcs[j + 4] * 128 + q * 8];
        uint2 u5 = *(const uint2*)&U8[(size_t)srcs[j + 5] * 128 + q * 8];
        uint2 u6 = *(const uint2*)&U8[(size_t)srcs[j + 6] * 128 + q * 8];
        uint2 u7 = *(const uint2*)&U8[(size_t)srcs[j + 7] * 128 + q * 8];
        float p0 = 0.f, p1 = 0.f, p2 = 0.f, p3 = 0.f;
        float p4 = 0.f, p5 = 0.f, p6 = 0.f, p7 = 0.f;
        EDOT(p0, u0); EDOT(p1, u1); EDOT(p2, u2); EDOT(p3, u3);
        EDOT(p4, u4); EDOT(p5, u5); EDOT(p6, u6); EDOT(p7, u7);
        #pragma unroll
        for (int off = 1; off < 16; off <<= 1) {
            p0 += __shfl_xor(p0, off); p1 += __shfl_xor(p1, off);
            p2 += __shfl_xor(p2, off); p3 += __shfl_xor(p3, off);
            p4 += __shfl_xor(p4, off); p5 += __shfl_xor(p5, off);
            p6 += __shfl_xor(p6, off); p7 += __shfl_xor(p7, off);
        }
        if (q == 0) {
            out[eids[j]]     = 1.0f / (1.0f + expf(-(p0 + bb)));
            out[eids[j + 1]] = 1.0f / (1.0f + expf(-(p1 + bb)));
            out[eids[j + 2]] = 1.0f / (1.0f + expf(-(p2 + bb)));
            out[eids[j + 3]] = 1.0f / (1.0f + expf(-(p3 + bb)));
            out[eids[j + 4]] = 1.0f / (1.0f + expf(-(p4 + bb)));
            out[eids[j + 5]] = 1.0f / (1.0f + expf(-(p5 + bb)));
            out[eids[j + 6]] = 1.0f / (1.0f + expf(-(p6 + bb)));
            out[eids[j + 7]] = 1.0f / (1.0f + expf(-(p7 + bb)));
        }
    }
    for (; j + 3 < e; j += 4) {
        uint2 u0 = *(const uint2*)&U8[(size_t)srcs[j]     * 128 + q * 8];
        uint2 u1 = *(const uint2*)&U8[(size_t)srcs[j + 1] * 128 + q * 8];
        uint2 u2 = *(const uint2*)&U8[(size_t)srcs[j + 2] * 128 + q * 8];
        uint2 u3 = *(const uint2*)&U8[(size_t)srcs[j + 3] * 128 + q * 8];
        float p0 = 0.f, p1 = 0.f, p2 = 0.f, p3 = 0.f;
        EDOT(p0, u0); EDOT(p1, u1); EDOT(p2, u2); EDOT(p3, u3);
        #pragma unroll
        for (int off = 1; off < 16; off <<= 1) {
            p0 += __shfl_xor(p0, off); p1 += __shfl_xor(p1, off);
            p2 += __shfl_xor(p2, off); p3 += __shfl_xor(p3, off);
        }
        if (q == 0) {
            out[eids[j]]     = 1.0f / (1.0f + expf(-(p0 + bb)));
            out[eids[j + 1]] = 1.0f / (1.0f + expf(-(p1 + bb)));
            out[eids[j + 2]] = 1.0f / (1.0f + expf(-(p2 + bb)));
            out[eids[j + 3]] = 1.0f / (1.0f + expf(-(p3 + bb)));
        }
    }
    for (; j < e; ++j) {
        uint2 u0 = *(const uint2*)&U8[(size_t)srcs[j] * 128 + q * 8];
        float p0 = 0.f;
        EDOT(p0, u0);
        #pragma unroll
        for (int off = 1; off < 16; off <<= 1) p0 += __shfl_xor(p0, off);
        if (q == 0) out[eids[j]] = 1.0f / (1.0f + expf(-(p0 + bb)));
    }
}

extern "C" void kernel_launch(void* const* d_in, const int* in_sizes, int n_in,
                              void* d_out, int out_size, void* d_ws, size_t ws_size,
                              hipStream_t stream) {
    const float* x   = (const float*)d_in[0];
    const int*   ei  = (const int*)d_in[1];
    const int*   src = ei;
    const int*   dst = ei + NE;
    const float* W1l = (const float*)d_in[2];
    const float* b1l = (const float*)d_in[3];
    const float* W1r = (const float*)d_in[4];
    const float* W2l = (const float*)d_in[5];
    const float* b2l = (const float*)d_in[6];
    const float* W2r = (const float*)d_in[7];
    const float* Wm1 = (const float*)d_in[8];
    const float* bm1 = (const float*)d_in[9];
    const float* Wm2 = (const float*)d_in[10];
    const float* bm2 = (const float*)d_in[11];
    float* out = (float*)d_out;

    char* ws = (char*)d_ws;
    int* rs   = (int*)(ws + OFF_RS);
    int* cnt  = (int*)(ws + OFF_CNT);
    int* cur  = (int*)(ws + OFF_CUR);    // row_end after scatter_idx
    int* bsum = (int*)(ws + OFF_BS);
    unsigned short* wb = (unsigned short*)(ws + OFF_WB);
    int* srcs = (int*)(ws + OFF_SRC);
    int* eids = (int*)(ws + OFF_EID);
    unsigned short* B0 = (unsigned short*)(ws + OFF_B0);  // xb, later Vb
    unsigned short* B2 = (unsigned short*)(ws + OFF_B2);  // h1b (root reads)
    unsigned char*  X8 = (unsigned char*)(ws + OFF_X8);   // fp8 x
    unsigned char*  H8 = (unsigned char*)(ws + OFF_H8);   // fp8 h1
    unsigned char*  U8 = (unsigned char*)(ws + OFF_U8);   // fp8 U

    unsigned short* W1lb = wb;
    unsigned short* W1rb = wb + 16384;
    unsigned short* W2lb = wb + 32768;
    unsigned short* W2rb = wb + 49152;
    unsigned short* Wm1b = wb + 65536;

    const int NB = 391;               // ceil(NN/256)
    const int NB64 = (NN + 63) / 64;  // 1563

    hipMemsetAsync(cnt, 0, NN * sizeof(int), stream);
    k_prep<<<12500 + 384 + 3125, 256, 0, stream>>>(x, B0, (unsigned*)X8,
                                                   W1l, W1r, W2l, W2r, Wm1,
                                                   wb, dst, cnt);
    k_scan1<<<NB, 256, 0, stream>>>(cnt, bsum);
    k_scan2<<<1, 512, 0, stream>>>(bsum, NB);
    k_scan3<<<NB, 256, 0, stream>>>(cnt, bsum, rs, cur);
    k_scatter_idx<<<(NE + 255) / 256, 256, 0, stream>>>(src, dst, cur, srcs, eids);

    k_aggconv1<<<NB64, 512, 0, stream>>>(B0, X8, rs, cur, srcs,
                                         W1lb, W1rb, b1l, B2, H8);         // h1 -> B2 + H8
    k_aggconv2uv<<<NB64, 512, 0, stream>>>(B2, H8, rs, cur, srcs,
                                           W2lb, W2rb, b2l, Wm1b, bm1,
                                           U8, B0);                        // U -> U8, V -> B0
    k_edge2<<<(NN * 16 + 255) / 256, 256, 0, stream>>>(U8, B0, rs, cur, srcs, eids,
                                                       Wm2, bm2, out);
}

// Round 13
// 264.432 us; speedup vs baseline: 1.1217x; 1.1217x over previous
//
#include <hip/hip_runtime.h>
#include <math.h>

#define NN 100000
#define NE 800000
#define D 128

typedef __attribute__((ext_vector_type(8))) short bf16x8;
typedef __attribute__((ext_vector_type(8))) unsigned short u16x8;
typedef __attribute__((ext_vector_type(4))) float f32x4;
typedef __attribute__((ext_vector_type(2))) float f32x2;

// ---- workspace layout (bytes) ----
constexpr size_t OFF_RS  = 0;                         // int[NN+1]
constexpr size_t OFF_CNT = 512 * 1024;                // int[NN] histogram
constexpr size_t OFF_CUR = 1024 * 1024;               // int[NN] cursor -> row_end
constexpr size_t OFF_BS  = 1536 * 1024;               // int[512] block sums
constexpr size_t OFF_WB  = 1552 * 1024;               // bf16 weights (98304 elems)
constexpr size_t OFF_SRC = 2 * 1024 * 1024;           // int[NE]
constexpr size_t OFF_EID = 6 * 1024 * 1024;           // int[NE]
constexpr size_t OFF_B0  = 10 * 1024 * 1024;          // bf16[100096*128] Vb
constexpr size_t OFF_X8  = OFF_B0 + 26 * 1024 * 1024; // fp8 x   [NN*128]
constexpr size_t OFF_H8  = OFF_X8 + 13 * 1024 * 1024; // fp8 h1  [NN*128]
constexpr size_t OFF_U8  = OFF_H8 + 13 * 1024 * 1024; // fp8 U   [NN*128]

__device__ __forceinline__ unsigned short f2b(float f) {
    unsigned u = __builtin_bit_cast(unsigned, f);
    return (unsigned short)((u + 0x7FFFu + ((u >> 16) & 1u)) >> 16);
}
__device__ __forceinline__ float b2f(unsigned short h) {
    unsigned u = ((unsigned)h) << 16;
    return __builtin_bit_cast(float, u);
}

// ------------- fused prep: x->fp8 | weights->bf16 | degree histogram --------
__global__ __launch_bounds__(256) void k_prep(const float* __restrict__ x,
                                              unsigned* __restrict__ x8w,
                                              const float* __restrict__ W1l,
                                              const float* __restrict__ W1r,
                                              const float* __restrict__ W2l,
                                              const float* __restrict__ W2r,
                                              const float* __restrict__ Wm1,
                                              unsigned short* __restrict__ wb,
                                              const int* __restrict__ dst,
                                              int* __restrict__ cnt) {
    int bid = blockIdx.x, tid = threadIdx.x;
    if (bid < 12500) {                       // x conversion, float4 granules
        int i = bid * 256 + tid;             // 3,200,000 = NN*D/4 exactly
        float4 v = *(const float4*)&x[(size_t)i * 4];
        unsigned p = __builtin_amdgcn_cvt_pk_fp8_f32(v.x, v.y, 0u, false);
        p = __builtin_amdgcn_cvt_pk_fp8_f32(v.z, v.w, p, true);
        x8w[i] = p;
    } else if (bid < 12884) {                // weights: 98304 elems
        int i = (bid - 12500) * 256 + tid;
        float v;
        if (i < 16384) v = W1l[i];
        else if (i < 32768) v = W1r[i - 16384];
        else if (i < 49152) v = W2l[i - 32768];
        else if (i < 65536) v = W2r[i - 49152];
        else v = Wm1[i - 65536];
        wb[i] = f2b(v);
    } else {                                 // degree histogram
        int e = (bid - 12884) * 256 + tid;
        atomicAdd(&cnt[dst[e]], 1);
    }
}

// ---------------- CSR scan chain ----------------
__global__ __launch_bounds__(256) void k_scan1(const int* __restrict__ cnt,
                                               int* __restrict__ bsum) {
    int i = blockIdx.x * 256 + threadIdx.x;
    int v = (i < NN) ? cnt[i] : 0;
    #pragma unroll
    for (int o = 1; o < 64; o <<= 1) v += __shfl_xor(v, o);
    __shared__ int wsum[4];
    if ((threadIdx.x & 63) == 0) wsum[threadIdx.x >> 6] = v;
    __syncthreads();
    if (threadIdx.x == 0) bsum[blockIdx.x] = wsum[0] + wsum[1] + wsum[2] + wsum[3];
}

__global__ __launch_bounds__(512) void k_scan2(int* __restrict__ bsum, int nb) {
    __shared__ int s[512];
    int t = threadIdx.x;
    int v = (t < nb) ? bsum[t] : 0;
    s[t] = v;
    __syncthreads();
    for (int o = 1; o < 512; o <<= 1) {
        int u = (t >= o) ? s[t - o] : 0;
        __syncthreads();
        s[t] += u;
        __syncthreads();
    }
    if (t < nb) bsum[t] = s[t] - v;   // exclusive
}

__global__ __launch_bounds__(256) void k_scan3(const int* __restrict__ cnt,
                                               const int* __restrict__ bsum,
                                               int* __restrict__ rs,
                                               int* __restrict__ cur) {
    __shared__ int s[256];
    int t = threadIdx.x;
    int i = blockIdx.x * 256 + t;
    int v = (i < NN) ? cnt[i] : 0;
    s[t] = v;
    __syncthreads();
    for (int o = 1; o < 256; o <<= 1) {
        int u = (t >= o) ? s[t - o] : 0;
        __syncthreads();
        s[t] += u;
        __syncthreads();
    }
    int ex = s[t] - v + bsum[blockIdx.x];
    if (i < NN) { rs[i] = ex; cur[i] = ex; }
    if (i == NN - 1) rs[NN] = ex + v;
}

__global__ __launch_bounds__(256) void k_scatter_idx(const int* __restrict__ src,
                                                     const int* __restrict__ dst,
                                                     int* __restrict__ cur,
                                                     int* __restrict__ srcs,
                                                     int* __restrict__ eids) {
    int e = blockIdx.x * 256 + threadIdx.x;
    if (e < NE) {
        int pos = atomicAdd(&cur[dst[e]], 1);
        srcs[pos] = src[e];
        eids[pos] = e;
    }
}

// ---- gather-mean (fp8 rows) for 64 nodes into LDS tile [64][136] bf16 -----
// 16 lanes/node, 8B (8 fp8) per lane per edge, 8-deep unrolled. (round-10)
#define UNPK8(acc, u) {                                               \
    f32x2 p0 = __builtin_amdgcn_cvt_pk_f32_fp8(u.x, false);           \
    f32x2 p1 = __builtin_amdgcn_cvt_pk_f32_fp8(u.x, true);            \
    f32x2 p2 = __builtin_amdgcn_cvt_pk_f32_fp8(u.y, false);           \
    f32x2 p3 = __builtin_amdgcn_cvt_pk_f32_fp8(u.y, true);            \
    acc[0] += p0.x; acc[1] += p0.y; acc[2] += p1.x; acc[3] += p1.y;   \
    acc[4] += p2.x; acc[5] += p2.y; acc[6] += p3.x; acc[7] += p3.y; }

__device__ __forceinline__ void gather_mean64(const unsigned char* __restrict__ feat8,
                                              const int* __restrict__ rs,
                                              const int* __restrict__ re,
                                              const int* __restrict__ srcs,
                                              int n0, unsigned short* agt) {
    const int tid = threadIdx.x;
    const int g = tid >> 4, q = tid & 15;   // g in 0..31
    #pragma unroll
    for (int half = 0; half < 2; ++half) {
        int r = half * 32 + g;
        int n = n0 + r;
        if (n > NN - 1) n = NN - 1;          // tail clamp (NN%64==32)
        int b = rs[n], e = re[n];
        float a0[8] = {}, a1[8] = {}, a2[8] = {}, a3[8] = {};
        int j = b;
        for (; j + 7 < e; j += 8) {
            uint2 v0 = *(const uint2*)&feat8[(size_t)srcs[j]     * 128 + q * 8];
            uint2 v1 = *(const uint2*)&feat8[(size_t)srcs[j + 1] * 128 + q * 8];
            uint2 v2 = *(const uint2*)&feat8[(size_t)srcs[j + 2] * 128 + q * 8];
            uint2 v3 = *(const uint2*)&feat8[(size_t)srcs[j + 3] * 128 + q * 8];
            uint2 v4 = *(const uint2*)&feat8[(size_t)srcs[j + 4] * 128 + q * 8];
            uint2 v5 = *(const uint2*)&feat8[(size_t)srcs[j + 5] * 128 + q * 8];
            uint2 v6 = *(const uint2*)&feat8[(size_t)srcs[j + 6] * 128 + q * 8];
            uint2 v7 = *(const uint2*)&feat8[(size_t)srcs[j + 7] * 128 + q * 8];
            UNPK8(a0, v0); UNPK8(a1, v1); UNPK8(a2, v2); UNPK8(a3, v3);
            UNPK8(a0, v4); UNPK8(a1, v5); UNPK8(a2, v6); UNPK8(a3, v7);
        }
        for (; j + 3 < e; j += 4) {
            uint2 v0 = *(const uint2*)&feat8[(size_t)srcs[j]     * 128 + q * 8];
            uint2 v1 = *(const uint2*)&feat8[(size_t)srcs[j + 1] * 128 + q * 8];
            uint2 v2 = *(const uint2*)&feat8[(size_t)srcs[j + 2] * 128 + q * 8];
            uint2 v3 = *(const uint2*)&feat8[(size_t)srcs[j + 3] * 128 + q * 8];
            UNPK8(a0, v0); UNPK8(a1, v1); UNPK8(a2, v2); UNPK8(a3, v3);
        }
        for (; j < e; ++j) {
            uint2 v0 = *(const uint2*)&feat8[(size_t)srcs[j] * 128 + q * 8];
            UNPK8(a0, v0);
        }
        float inv = 1.0f / fmaxf((float)(e - b), 1.0f);
        u16x8 o;
        #pragma unroll
        for (int i = 0; i < 8; ++i) o[i] = f2b((a0[i] + a1[i] + a2[i] + a3[i]) * inv);
        *(u16x8*)&agt[r * 136 + q * 8] = o;
    }
}

// stage 64 fp8 rows -> LDS tile [64][136] bf16 (coalesced 16B/lane, clamped)
__device__ __forceinline__ void stage_tile_fp8in(const unsigned char* __restrict__ src8,
                                                 int n0, unsigned short* t) {
    const int tid = threadIdx.x;          // 512 thr x 16B = 8192B = whole tile
    int r = tid >> 3, q = tid & 7;
    int gr = n0 + r;
    if (gr > NN - 1) gr = NN - 1;
    uint4 v = *(const uint4*)&src8[(size_t)gr * 128 + q * 16];
    u16x8 o0, o1;
    f32x2 p;
    p = __builtin_amdgcn_cvt_pk_f32_fp8(v.x, false); o0[0] = f2b(p.x); o0[1] = f2b(p.y);
    p = __builtin_amdgcn_cvt_pk_f32_fp8(v.x, true);  o0[2] = f2b(p.x); o0[3] = f2b(p.y);
    p = __builtin_amdgcn_cvt_pk_f32_fp8(v.y, false); o0[4] = f2b(p.x); o0[5] = f2b(p.y);
    p = __builtin_amdgcn_cvt_pk_f32_fp8(v.y, true);  o0[6] = f2b(p.x); o0[7] = f2b(p.y);
    p = __builtin_amdgcn_cvt_pk_f32_fp8(v.z, false); o1[0] = f2b(p.x); o1[1] = f2b(p.y);
    p = __builtin_amdgcn_cvt_pk_f32_fp8(v.z, true);  o1[2] = f2b(p.x); o1[3] = f2b(p.y);
    p = __builtin_amdgcn_cvt_pk_f32_fp8(v.w, false); o1[4] = f2b(p.x); o1[5] = f2b(p.y);
    p = __builtin_amdgcn_cvt_pk_f32_fp8(v.w, true);  o1[6] = f2b(p.x); o1[7] = f2b(p.y);
    *(u16x8*)&t[r * 136 + q * 16]     = o0;
    *(u16x8*)&t[r * 136 + q * 16 + 8] = o1;
}

// store LDS tile [64][136] -> global bf16 (coalesced, guarded)
__device__ __forceinline__ void store_tile(const unsigned short* t,
                                           int n0, unsigned short* __restrict__ dstp) {
    const int tid = threadIdx.x;
    #pragma unroll
    for (int it = 0; it < 2; ++it) {
        int idx = it * 512 + tid;
        int r = idx >> 4, c = (idx & 15) * 8;
        int gr = n0 + r;
        if (gr < NN)
            *(u16x8*)&dstp[(size_t)gr * D + c] = *(const u16x8*)&t[r * 136 + c];
    }
}

// store LDS bf16 tile -> global fp8 (coalesced 4B words, guarded)
__device__ __forceinline__ void store_tile_fp8(const unsigned short* t,
                                               int n0, unsigned char* __restrict__ dst8) {
    const int tid = threadIdx.x;
    #pragma unroll
    for (int it = 0; it < 4; ++it) {
        int w = it * 512 + tid;          // word 0..2047
        int r = w >> 5, c4 = (w & 31) * 4;
        int gr = n0 + r;
        if (gr < NN) {
            unsigned p = __builtin_amdgcn_cvt_pk_fp8_f32(
                b2f(t[r * 136 + c4 + 0]), b2f(t[r * 136 + c4 + 1]), 0u, false);
            p = __builtin_amdgcn_cvt_pk_fp8_f32(
                b2f(t[r * 136 + c4 + 2]), b2f(t[r * 136 + c4 + 3]), p, true);
            *(unsigned*)&dst8[(size_t)gr * 128 + c4] = p;
        }
    }
}

// ---------------- fused agg + conv1: h1 = relu(mean@W1l^T + b + x@W1r^T) ----
__global__ __launch_bounds__(512) void k_aggconv1(const unsigned char* __restrict__ x8,
                                                  const int* __restrict__ rs,
                                                  const int* __restrict__ re,
                                                  const int* __restrict__ srcs,
                                                  const unsigned short* __restrict__ Wlb,
                                                  const unsigned short* __restrict__ Wrb,
                                                  const float* __restrict__ bias,
                                                  unsigned char* __restrict__ h8) {
    __shared__ unsigned short agt[64 * 136];
    __shared__ unsigned short sto[64 * 136];
    const int tid = threadIdx.x;
    const int n0 = blockIdx.x * 64;

    stage_tile_fp8in(x8, n0, sto);
    gather_mean64(x8, rs, re, srcs, n0, agt);
    __syncthreads();

    const int wv = tid >> 6, l = tid & 63;
    const int lrow = l & 15, lk = (l >> 4) * 8;
    f32x4 acc[4] = {};
    #pragma unroll
    for (int p = 0; p < 2; ++p) {
        const unsigned short* W  = p ? Wrb : Wlb;
        const unsigned short* At = p ? sto : agt;
        #pragma unroll
        for (int ks = 0; ks < 4; ++ks) {
            bf16x8 bfr = *(const bf16x8*)&W[(size_t)(wv * 16 + lrow) * D + ks * 32 + lk];
            #pragma unroll
            for (int mt = 0; mt < 4; ++mt) {
                bf16x8 af = *(const bf16x8*)&At[(mt * 16 + lrow) * 136 + ks * 32 + lk];
                acc[mt] = __builtin_amdgcn_mfma_f32_16x16x32_bf16(af, bfr, acc[mt], 0, 0, 0);
            }
        }
    }
    __syncthreads();   // all sto (x-tile) reads done before overwrite
    const int orow = (l >> 4) * 4, ocol = l & 15;
    float bb = bias[wv * 16 + ocol];
    #pragma unroll
    for (int mt = 0; mt < 4; ++mt)
        #pragma unroll
        for (int j = 0; j < 4; ++j)
            sto[(mt * 16 + orow + j) * 136 + wv * 16 + ocol] =
                f2b(fmaxf(acc[mt][j] + bb, 0.0f));
    __syncthreads();
    store_tile_fp8(sto, n0, h8);
}

// ------- fused agg + conv2 + U/V: h2 in LDS; U -> fp8, V -> bf16 -------
__global__ __launch_bounds__(512) void k_aggconv2uv(const unsigned char* __restrict__ h8,
                                                    const int* __restrict__ rs,
                                                    const int* __restrict__ re,
                                                    const int* __restrict__ srcs,
                                                    const unsigned short* __restrict__ Wlb,
                                                    const unsigned short* __restrict__ Wrb,
                                                    const float* __restrict__ bias,
                                                    const unsigned short* __restrict__ Wm1b,
                                                    const float* __restrict__ bm1,
                                                    unsigned char* __restrict__ U8,
                                                    unsigned short* __restrict__ Vb) {
    __shared__ unsigned short agt[64 * 136];
    __shared__ unsigned short sto[64 * 136];
    const int tid = threadIdx.x;
    const int n0 = blockIdx.x * 64;

    stage_tile_fp8in(h8, n0, sto);            // h1 root tile -> sto
    gather_mean64(h8, rs, re, srcs, n0, agt); // fp8 gather
    __syncthreads();                          // (a)

    const int wv = tid >> 6, l = tid & 63;
    const int lrow = l & 15, lk = (l >> 4) * 8;
    const int orow = (l >> 4) * 4, ocol = l & 15;

    // phase 1: h2 = relu(agg@W2l^T + b + h1@W2r^T)
    f32x4 acc[4] = {};
    #pragma unroll
    for (int p = 0; p < 2; ++p) {
        const unsigned short* W  = p ? Wrb : Wlb;
        const unsigned short* At = p ? sto : agt;
        #pragma unroll
        for (int ks = 0; ks < 4; ++ks) {
            bf16x8 bfr = *(const bf16x8*)&W[(size_t)(wv * 16 + lrow) * D + ks * 32 + lk];
            #pragma unroll
            for (int mt = 0; mt < 4; ++mt) {
                bf16x8 af = *(const bf16x8*)&At[(mt * 16 + lrow) * 136 + ks * 32 + lk];
                acc[mt] = __builtin_amdgcn_mfma_f32_16x16x32_bf16(af, bfr, acc[mt], 0, 0, 0);
            }
        }
    }
    __syncthreads();                          // (b) all agt/sto reads done
    {   // h2 epilogue -> agt
        float bb = bias[wv * 16 + ocol];
        #pragma unroll
        for (int mt = 0; mt < 4; ++mt)
            #pragma unroll
            for (int j = 0; j < 4; ++j)
                agt[(mt * 16 + orow + j) * 136 + wv * 16 + ocol] =
                    f2b(fmaxf(acc[mt][j] + bb, 0.0f));
    }
    __syncthreads();                          // (c) h2 tile complete in agt

    f32x4 aU[4] = {}, aV[4] = {};
    #pragma unroll
    for (int ks = 0; ks < 4; ++ks) {
        bf16x8 bu = *(const bf16x8*)&Wm1b[(size_t)(wv * 16 + lrow) * 256 + ks * 32 + lk];
        bf16x8 bv = *(const bf16x8*)&Wm1b[(size_t)(wv * 16 + lrow) * 256 + 128 + ks * 32 + lk];
        #pragma unroll
        for (int mt = 0; mt < 4; ++mt) {
            bf16x8 af = *(const bf16x8*)&agt[(mt * 16 + lrow) * 136 + ks * 32 + lk];
            aU[mt] = __builtin_amdgcn_mfma_f32_16x16x32_bf16(af, bu, aU[mt], 0, 0, 0);
            aV[mt] = __builtin_amdgcn_mfma_f32_16x16x32_bf16(af, bv, aV[mt], 0, 0, 0);
        }
    }
    {   // stage U -> sto (root-tile reads ended at (b))
        float bb = bm1[wv * 16 + ocol];
        #pragma unroll
        for (int mt = 0; mt < 4; ++mt)
            #pragma unroll
            for (int j = 0; j < 4; ++j)
                sto[(mt * 16 + orow + j) * 136 + wv * 16 + ocol] = f2b(aU[mt][j] + bb);
    }
    __syncthreads();                          // (d) U staged; all agt (h2) reads done
    store_tile_fp8(sto, n0, U8);              // U only as fp8
    {   // stage V -> agt
        #pragma unroll
        for (int mt = 0; mt < 4; ++mt)
            #pragma unroll
            for (int j = 0; j < 4; ++j)
                agt[(mt * 16 + orow + j) * 136 + wv * 16 + ocol] = f2b(aV[mt][j]);
    }
    __syncthreads();                          // (e)
    store_tile(agt, n0, Vb);
}

// ---------------- edge finalize, dst-grouped (round-10 proven), fp8 U ------
__global__ __launch_bounds__(256) void k_edge2(const unsigned char* __restrict__ U8,
                                               const unsigned short* __restrict__ Vb,
                                               const int* __restrict__ rs,
                                               const int* __restrict__ re,
                                               const int* __restrict__ srcs,
                                               const int* __restrict__ eids,
                                               const float* __restrict__ wm2,
                                               const float* __restrict__ bm2,
                                               float* __restrict__ out) {
    int t = blockIdx.x * 256 + threadIdx.x;
    int g = t >> 4, q = t & 15;
    if (g >= NN) return;
    int b = rs[g], e = re[g];
    if (b == e) return;
    u16x8 vv = *(const u16x8*)&Vb[(size_t)g * D + q * 8];
    float vf[8], wf[8];
    #pragma unroll
    for (int i = 0; i < 8; ++i) vf[i] = b2f(vv[i]);
    float4 w0 = *(const float4*)&wm2[q * 8];
    float4 w1 = *(const float4*)&wm2[q * 8 + 4];
    wf[0] = w0.x; wf[1] = w0.y; wf[2] = w0.z; wf[3] = w0.w;
    wf[4] = w1.x; wf[5] = w1.y; wf[6] = w1.z; wf[7] = w1.w;
    const float bb = bm2[0];

#define EDOT(p, u) {                                                   \
    f32x2 q0 = __builtin_amdgcn_cvt_pk_f32_fp8(u.x, false);            \
    f32x2 q1 = __builtin_amdgcn_cvt_pk_f32_fp8(u.x, true);             \
    f32x2 q2 = __builtin_amdgcn_cvt_pk_f32_fp8(u.y, false);            \
    f32x2 q3 = __builtin_amdgcn_cvt_pk_f32_fp8(u.y, true);             \
    p += fmaxf(q0.x + vf[0], 0.0f) * wf[0] + fmaxf(q0.y + vf[1], 0.0f) * wf[1] \
       + fmaxf(q1.x + vf[2], 0.0f) * wf[2] + fmaxf(q1.y + vf[3], 0.0f) * wf[3] \
       + fmaxf(q2.x + vf[4], 0.0f) * wf[4] + fmaxf(q2.y + vf[5], 0.0f) * wf[5] \
       + fmaxf(q3.x + vf[6], 0.0f) * wf[6] + fmaxf(q3.y + vf[7], 0.0f) * wf[7]; }

    int j = b;
    for (; j + 7 < e; j += 8) {
        uint2 u0 = *(const uint2*)&U8[(size_t)srcs[j]     * 128 + q * 8];
        uint2 u1 = *(const uint2*)&U8[(size_t)srcs[j + 1] * 128 + q * 8];
        uint2 u2 = *(const uint2*)&U8[(size_t)srcs[j + 2] * 128 + q * 8];
        uint2 u3 = *(const uint2*)&U8[(size_t)srcs[j + 3] * 128 + q * 8];
        uint2 u4 = *(const uint2*)&U8[(size_t)srcs[j + 4] * 128 + q * 8];
        uint2 u5 = *(const uint2*)&U8[(size_t)srcs[j + 5] * 128 + q * 8];
        uint2 u6 = *(const uint2*)&U8[(size_t)srcs[j + 6] * 128 + q * 8];
        uint2 u7 = *(const uint2*)&U8[(size_t)srcs[j + 7] * 128 + q * 8];
        float p0 = 0.f, p1 = 0.f, p2 = 0.f, p3 = 0.f;
        float p4 = 0.f, p5 = 0.f, p6 = 0.f, p7 = 0.f;
        EDOT(p0, u0); EDOT(p1, u1); EDOT(p2, u2); EDOT(p3, u3);
        EDOT(p4, u4); EDOT(p5, u5); EDOT(p6, u6); EDOT(p7, u7);
        #pragma unroll
        for (int off = 1; off < 16; off <<= 1) {
            p0 += __shfl_xor(p0, off); p1 += __shfl_xor(p1, off);
            p2 += __shfl_xor(p2, off); p3 += __shfl_xor(p3, off);
            p4 += __shfl_xor(p4, off); p5 += __shfl_xor(p5, off);
            p6 += __shfl_xor(p6, off); p7 += __shfl_xor(p7, off);
        }
        if (q == 0) {
            out[eids[j]]     = 1.0f / (1.0f + expf(-(p0 + bb)));
            out[eids[j + 1]] = 1.0f / (1.0f + expf(-(p1 + bb)));
            out[eids[j + 2]] = 1.0f / (1.0f + expf(-(p2 + bb)));
            out[eids[j + 3]] = 1.0f / (1.0f + expf(-(p3 + bb)));
            out[eids[j + 4]] = 1.0f / (1.0f + expf(-(p4 + bb)));
            out[eids[j + 5]] = 1.0f / (1.0f + expf(-(p5 + bb)));
            out[eids[j + 6]] = 1.0f / (1.0f + expf(-(p6 + bb)));
            out[eids[j + 7]] = 1.0f / (1.0f + expf(-(p7 + bb)));
        }
    }
    for (; j + 3 < e; j += 4) {
        uint2 u0 = *(const uint2*)&U8[(size_t)srcs[j]     * 128 + q * 8];
        uint2 u1 = *(const uint2*)&U8[(size_t)srcs[j + 1] * 128 + q * 8];
        uint2 u2 = *(const uint2*)&U8[(size_t)srcs[j + 2] * 128 + q * 8];
        uint2 u3 = *(const uint2*)&U8[(size_t)srcs[j + 3] * 128 + q * 8];
        float p0 = 0.f, p1 = 0.f, p2 = 0.f, p3 = 0.f;
        EDOT(p0, u0); EDOT(p1, u1); EDOT(p2, u2); EDOT(p3, u3);
        #pragma unroll
        for (int off = 1; off < 16; off <<= 1) {
            p0 += __shfl_xor(p0, off); p1 += __shfl_xor(p1, off);
            p2 += __shfl_xor(p2, off); p3 += __shfl_xor(p3, off);
        }
        if (q == 0) {
            out[eids[j]]     = 1.0f / (1.0f + expf(-(p0 + bb)));
            out[eids[j + 1]] = 1.0f / (1.0f + expf(-(p1 + bb)));
            out[eids[j + 2]] = 1.0f / (1.0f + expf(-(p2 + bb)));
            out[eids[j + 3]] = 1.0f / (1.0f + expf(-(p3 + bb)));
        }
    }
    for (; j < e; ++j) {
        uint2 u0 = *(const uint2*)&U8[(size_t)srcs[j] * 128 + q * 8];
        float p0 = 0.f;
        EDOT(p0, u0);
        #pragma unroll
        for (int off = 1; off < 16; off <<= 1) p0 += __shfl_xor(p0, off);
        if (q == 0) out[eids[j]] = 1.0f / (1.0f + expf(-(p0 + bb)));
    }
}

extern "C" void kernel_launch(void* const* d_in, const int* in_sizes, int n_in,
                              void* d_out, int out_size, void* d_ws, size_t ws_size,
                              hipStream_t stream) {
    const float* x   = (const float*)d_in[0];
    const int*   ei  = (const int*)d_in[1];
    const int*   src = ei;
    const int*   dst = ei + NE;
    const float* W1l = (const float*)d_in[2];
    const float* b1l = (const float*)d_in[3];
    const float* W1r = (const float*)d_in[4];
    const float* W2l = (const float*)d_in[5];
    const float* b2l = (const float*)d_in[6];
    const float* W2r = (const float*)d_in[7];
    const float* Wm1 = (const float*)d_in[8];
    const float* bm1 = (const float*)d_in[9];
    const float* Wm2 = (const float*)d_in[10];
    const float* bm2 = (const float*)d_in[11];
    float* out = (float*)d_out;

    char* ws = (char*)d_ws;
    int* rs   = (int*)(ws + OFF_RS);
    int* cnt  = (int*)(ws + OFF_CNT);
    int* cur  = (int*)(ws + OFF_CUR);    // row_end after scatter_idx
    int* bsum = (int*)(ws + OFF_BS);
    unsigned short* wb = (unsigned short*)(ws + OFF_WB);
    int* srcs = (int*)(ws + OFF_SRC);
    int* eids = (int*)(ws + OFF_EID);
    unsigned short* B0 = (unsigned short*)(ws + OFF_B0);  // Vb
    unsigned char*  X8 = (unsigned char*)(ws + OFF_X8);   // fp8 x
    unsigned char*  H8 = (unsigned char*)(ws + OFF_H8);   // fp8 h1
    unsigned char*  U8 = (unsigned char*)(ws + OFF_U8);   // fp8 U

    unsigned short* W1lb = wb;
    unsigned short* W1rb = wb + 16384;
    unsigned short* W2lb = wb + 32768;
    unsigned short* W2rb = wb + 49152;
    unsigned short* Wm1b = wb + 65536;

    const int NB = 391;               // ceil(NN/256)
    const int NB64 = (NN + 63) / 64;  // 1563

    hipMemsetAsync(cnt, 0, NN * sizeof(int), stream);
    k_prep<<<12500 + 384 + 3125, 256, 0, stream>>>(x, (unsigned*)X8,
                                                   W1l, W1r, W2l, W2r, Wm1,
                                                   wb, dst, cnt);
    k_scan1<<<NB, 256, 0, stream>>>(cnt, bsum);
    k_scan2<<<1, 512, 0, stream>>>(bsum, NB);
    k_scan3<<<NB, 256, 0, stream>>>(cnt, bsum, rs, cur);
    k_scatter_idx<<<(NE + 255) / 256, 256, 0, stream>>>(src, dst, cur, srcs, eids);

    k_aggconv1<<<NB64, 512, 0, stream>>>(X8, rs, cur, srcs,
                                         W1lb, W1rb, b1l, H8);             // h1 -> H8
    k_aggconv2uv<<<NB64, 512, 0, stream>>>(H8, rs, cur, srcs,
                                           W2lb, W2rb, b2l, Wm1b, bm1,
                                           U8, B0);                        // U -> U8, V -> B0
    k_edge2<<<(NN * 16 + 255) / 256, 256, 0, stream>>>(U8, B0, rs, cur, srcs, eids,
                                                       Wm2, bm2, out);
}

// Round 14
// 259.767 us; speedup vs baseline: 1.1418x; 1.0180x over previous
//
#include <hip/hip_runtime.h>
#include <math.h>

#define NN 100000
#define NE 800000
#define D 128

typedef __attribute__((ext_vector_type(8))) short bf16x8;
typedef __attribute__((ext_vector_type(8))) unsigned short u16x8;
typedef __attribute__((ext_vector_type(4))) float f32x4;
typedef __attribute__((ext_vector_type(2))) float f32x2;

// ---- workspace layout (bytes) ----
constexpr size_t OFF_RS  = 0;                         // int[NN+1]
constexpr size_t OFF_CNT = 512 * 1024;                // int[NN] histogram
constexpr size_t OFF_CUR = 1024 * 1024;               // int[NN] cursor -> row_end
constexpr size_t OFF_BS  = 1536 * 1024;               // int[512] block sums
constexpr size_t OFF_WB  = 1552 * 1024;               // bf16 weights (98304 elems)
constexpr size_t OFF_SRC = 2 * 1024 * 1024;           // int[NE]
constexpr size_t OFF_EID = 6 * 1024 * 1024;           // int[NE]
constexpr size_t OFF_V8  = 10 * 1024 * 1024;          // fp8 V   [NN*128]
constexpr size_t OFF_X8  = OFF_V8 + 13 * 1024 * 1024; // fp8 x   [NN*128]
constexpr size_t OFF_H8  = OFF_X8 + 13 * 1024 * 1024; // fp8 h1  [NN*128]
constexpr size_t OFF_U8  = OFF_H8 + 13 * 1024 * 1024; // fp8 U   [NN*128]

__device__ __forceinline__ unsigned short f2b(float f) {
    unsigned u = __builtin_bit_cast(unsigned, f);
    return (unsigned short)((u + 0x7FFFu + ((u >> 16) & 1u)) >> 16);
}
__device__ __forceinline__ float b2f(unsigned short h) {
    unsigned u = ((unsigned)h) << 16;
    return __builtin_bit_cast(float, u);
}

// ------------- fused prep: x->fp8 | weights->bf16 | degree histogram --------
__global__ __launch_bounds__(256) void k_prep(const float* __restrict__ x,
                                              unsigned* __restrict__ x8w,
                                              const float* __restrict__ W1l,
                                              const float* __restrict__ W1r,
                                              const float* __restrict__ W2l,
                                              const float* __restrict__ W2r,
                                              const float* __restrict__ Wm1,
                                              unsigned short* __restrict__ wb,
                                              const int* __restrict__ dst,
                                              int* __restrict__ cnt) {
    int bid = blockIdx.x, tid = threadIdx.x;
    if (bid < 12500) {                       // x conversion, float4 granules
        int i = bid * 256 + tid;             // 3,200,000 = NN*D/4 exactly
        float4 v = *(const float4*)&x[(size_t)i * 4];
        unsigned p = __builtin_amdgcn_cvt_pk_fp8_f32(v.x, v.y, 0u, false);
        p = __builtin_amdgcn_cvt_pk_fp8_f32(v.z, v.w, p, true);
        x8w[i] = p;
    } else if (bid < 12884) {                // weights: 98304 elems
        int i = (bid - 12500) * 256 + tid;
        float v;
        if (i < 16384) v = W1l[i];
        else if (i < 32768) v = W1r[i - 16384];
        else if (i < 49152) v = W2l[i - 32768];
        else if (i < 65536) v = W2r[i - 49152];
        else v = Wm1[i - 65536];
        wb[i] = f2b(v);
    } else {                                 // degree histogram
        int e = (bid - 12884) * 256 + tid;
        atomicAdd(&cnt[dst[e]], 1);
    }
}

// ---------------- CSR scan chain ----------------
__global__ __launch_bounds__(256) void k_scan1(const int* __restrict__ cnt,
                                               int* __restrict__ bsum) {
    int i = blockIdx.x * 256 + threadIdx.x;
    int v = (i < NN) ? cnt[i] : 0;
    #pragma unroll
    for (int o = 1; o < 64; o <<= 1) v += __shfl_xor(v, o);
    __shared__ int wsum[4];
    if ((threadIdx.x & 63) == 0) wsum[threadIdx.x >> 6] = v;
    __syncthreads();
    if (threadIdx.x == 0) bsum[blockIdx.x] = wsum[0] + wsum[1] + wsum[2] + wsum[3];
}

__global__ __launch_bounds__(512) void k_scan2(int* __restrict__ bsum, int nb) {
    __shared__ int s[512];
    int t = threadIdx.x;
    int v = (t < nb) ? bsum[t] : 0;
    s[t] = v;
    __syncthreads();
    for (int o = 1; o < 512; o <<= 1) {
        int u = (t >= o) ? s[t - o] : 0;
        __syncthreads();
        s[t] += u;
        __syncthreads();
    }
    if (t < nb) bsum[t] = s[t] - v;   // exclusive
}

__global__ __launch_bounds__(256) void k_scan3(const int* __restrict__ cnt,
                                               const int* __restrict__ bsum,
                                               int* __restrict__ rs,
                                               int* __restrict__ cur) {
    __shared__ int s[256];
    int t = threadIdx.x;
    int i = blockIdx.x * 256 + t;
    int v = (i < NN) ? cnt[i] : 0;
    s[t] = v;
    __syncthreads();
    for (int o = 1; o < 256; o <<= 1) {
        int u = (t >= o) ? s[t - o] : 0;
        __syncthreads();
        s[t] += u;
        __syncthreads();
    }
    int ex = s[t] - v + bsum[blockIdx.x];
    if (i < NN) { rs[i] = ex; cur[i] = ex; }
    if (i == NN - 1) rs[NN] = ex + v;
}

__global__ __launch_bounds__(256) void k_scatter_idx(const int* __restrict__ src,
                                                     const int* __restrict__ dst,
                                                     int* __restrict__ cur,
                                                     int* __restrict__ srcs,
                                                     int* __restrict__ eids) {
    int e = blockIdx.x * 256 + threadIdx.x;
    if (e < NE) {
        int pos = atomicAdd(&cur[dst[e]], 1);
        srcs[pos] = src[e];
        eids[pos] = e;
    }
}

// ---- gather-mean (fp8 rows) for 64 nodes into LDS tile [64][136] bf16 -----
// 16 lanes/node, 8B (8 fp8) per lane per edge, 8-deep unrolled. (round-10)
#define UNPK8(acc, u) {                                               \
    f32x2 p0 = __builtin_amdgcn_cvt_pk_f32_fp8(u.x, false);           \
    f32x2 p1 = __builtin_amdgcn_cvt_pk_f32_fp8(u.x, true);            \
    f32x2 p2 = __builtin_amdgcn_cvt_pk_f32_fp8(u.y, false);           \
    f32x2 p3 = __builtin_amdgcn_cvt_pk_f32_fp8(u.y, true);            \
    acc[0] += p0.x; acc[1] += p0.y; acc[2] += p1.x; acc[3] += p1.y;   \
    acc[4] += p2.x; acc[5] += p2.y; acc[6] += p3.x; acc[7] += p3.y; }

__device__ __forceinline__ void gather_mean64(const unsigned char* __restrict__ feat8,
                                              const int* __restrict__ rs,
                                              const int* __restrict__ re,
                                              const int* __restrict__ srcs,
                                              int n0, unsigned short* agt) {
    const int tid = threadIdx.x;
    const int g = tid >> 4, q = tid & 15;   // g in 0..31
    #pragma unroll
    for (int half = 0; half < 2; ++half) {
        int r = half * 32 + g;
        int n = n0 + r;
        if (n > NN - 1) n = NN - 1;          // tail clamp (NN%64==32)
        int b = rs[n], e = re[n];
        float a0[8] = {}, a1[8] = {}, a2[8] = {}, a3[8] = {};
        int j = b;
        for (; j + 7 < e; j += 8) {
            uint2 v0 = *(const uint2*)&feat8[(size_t)srcs[j]     * 128 + q * 8];
            uint2 v1 = *(const uint2*)&feat8[(size_t)srcs[j + 1] * 128 + q * 8];
            uint2 v2 = *(const uint2*)&feat8[(size_t)srcs[j + 2] * 128 + q * 8];
            uint2 v3 = *(const uint2*)&feat8[(size_t)srcs[j + 3] * 128 + q * 8];
            uint2 v4 = *(const uint2*)&feat8[(size_t)srcs[j + 4] * 128 + q * 8];
            uint2 v5 = *(const uint2*)&feat8[(size_t)srcs[j + 5] * 128 + q * 8];
            uint2 v6 = *(const uint2*)&feat8[(size_t)srcs[j + 6] * 128 + q * 8];
            uint2 v7 = *(const uint2*)&feat8[(size_t)srcs[j + 7] * 128 + q * 8];
            UNPK8(a0, v0); UNPK8(a1, v1); UNPK8(a2, v2); UNPK8(a3, v3);
            UNPK8(a0, v4); UNPK8(a1, v5); UNPK8(a2, v6); UNPK8(a3, v7);
        }
        for (; j + 3 < e; j += 4) {
            uint2 v0 = *(const uint2*)&feat8[(size_t)srcs[j]     * 128 + q * 8];
            uint2 v1 = *(const uint2*)&feat8[(size_t)srcs[j + 1] * 128 + q * 8];
            uint2 v2 = *(const uint2*)&feat8[(size_t)srcs[j + 2] * 128 + q * 8];
            uint2 v3 = *(const uint2*)&feat8[(size_t)srcs[j + 3] * 128 + q * 8];
            UNPK8(a0, v0); UNPK8(a1, v1); UNPK8(a2, v2); UNPK8(a3, v3);
        }
        for (; j < e; ++j) {
            uint2 v0 = *(const uint2*)&feat8[(size_t)srcs[j] * 128 + q * 8];
            UNPK8(a0, v0);
        }
        float inv = 1.0f / fmaxf((float)(e - b), 1.0f);
        u16x8 o;
        #pragma unroll
        for (int i = 0; i < 8; ++i) o[i] = f2b((a0[i] + a1[i] + a2[i] + a3[i]) * inv);
        *(u16x8*)&agt[r * 136 + q * 8] = o;
    }
}

// stage 64 fp8 rows -> LDS tile [64][136] bf16 (coalesced 16B/lane, clamped)
__device__ __forceinline__ void stage_tile_fp8in(const unsigned char* __restrict__ src8,
                                                 int n0, unsigned short* t) {
    const int tid = threadIdx.x;          // 512 thr x 16B = 8192B = whole tile
    int r = tid >> 3, q = tid & 7;
    int gr = n0 + r;
    if (gr > NN - 1) gr = NN - 1;
    uint4 v = *(const uint4*)&src8[(size_t)gr * 128 + q * 16];
    u16x8 o0, o1;
    f32x2 p;
    p = __builtin_amdgcn_cvt_pk_f32_fp8(v.x, false); o0[0] = f2b(p.x); o0[1] = f2b(p.y);
    p = __builtin_amdgcn_cvt_pk_f32_fp8(v.x, true);  o0[2] = f2b(p.x); o0[3] = f2b(p.y);
    p = __builtin_amdgcn_cvt_pk_f32_fp8(v.y, false); o0[4] = f2b(p.x); o0[5] = f2b(p.y);
    p = __builtin_amdgcn_cvt_pk_f32_fp8(v.y, true);  o0[6] = f2b(p.x); o0[7] = f2b(p.y);
    p = __builtin_amdgcn_cvt_pk_f32_fp8(v.z, false); o1[0] = f2b(p.x); o1[1] = f2b(p.y);
    p = __builtin_amdgcn_cvt_pk_f32_fp8(v.z, true);  o1[2] = f2b(p.x); o1[3] = f2b(p.y);
    p = __builtin_amdgcn_cvt_pk_f32_fp8(v.w, false); o1[4] = f2b(p.x); o1[5] = f2b(p.y);
    p = __builtin_amdgcn_cvt_pk_f32_fp8(v.w, true);  o1[6] = f2b(p.x); o1[7] = f2b(p.y);
    *(u16x8*)&t[r * 136 + q * 16]     = o0;
    *(u16x8*)&t[r * 136 + q * 16 + 8] = o1;
}

// store LDS bf16 tile -> global fp8 (coalesced 4B words, guarded)
__device__ __forceinline__ void store_tile_fp8(const unsigned short* t,
                                               int n0, unsigned char* __restrict__ dst8) {
    const int tid = threadIdx.x;
    #pragma unroll
    for (int it = 0; it < 4; ++it) {
        int w = it * 512 + tid;          // word 0..2047
        int r = w >> 5, c4 = (w & 31) * 4;
        int gr = n0 + r;
        if (gr < NN) {
            unsigned p = __builtin_amdgcn_cvt_pk_fp8_f32(
                b2f(t[r * 136 + c4 + 0]), b2f(t[r * 136 + c4 + 1]), 0u, false);
            p = __builtin_amdgcn_cvt_pk_fp8_f32(
                b2f(t[r * 136 + c4 + 2]), b2f(t[r * 136 + c4 + 3]), p, true);
            *(unsigned*)&dst8[(size_t)gr * 128 + c4] = p;
        }
    }
}

// ---------------- fused agg + conv1: h1 = relu(mean@W1l^T + b + x@W1r^T) ----
__global__ __launch_bounds__(512) void k_aggconv1(const unsigned char* __restrict__ x8,
                                                  const int* __restrict__ rs,
                                                  const int* __restrict__ re,
                                                  const int* __restrict__ srcs,
                                                  const unsigned short* __restrict__ Wlb,
                                                  const unsigned short* __restrict__ Wrb,
                                                  const float* __restrict__ bias,
                                                  unsigned char* __restrict__ h8) {
    __shared__ unsigned short agt[64 * 136];
    __shared__ unsigned short sto[64 * 136];
    const int tid = threadIdx.x;
    const int n0 = blockIdx.x * 64;

    stage_tile_fp8in(x8, n0, sto);
    gather_mean64(x8, rs, re, srcs, n0, agt);
    __syncthreads();

    const int wv = tid >> 6, l = tid & 63;
    const int lrow = l & 15, lk = (l >> 4) * 8;
    f32x4 acc[4] = {};
    #pragma unroll
    for (int p = 0; p < 2; ++p) {
        const unsigned short* W  = p ? Wrb : Wlb;
        const unsigned short* At = p ? sto : agt;
        #pragma unroll
        for (int ks = 0; ks < 4; ++ks) {
            bf16x8 bfr = *(const bf16x8*)&W[(size_t)(wv * 16 + lrow) * D + ks * 32 + lk];
            #pragma unroll
            for (int mt = 0; mt < 4; ++mt) {
                bf16x8 af = *(const bf16x8*)&At[(mt * 16 + lrow) * 136 + ks * 32 + lk];
                acc[mt] = __builtin_amdgcn_mfma_f32_16x16x32_bf16(af, bfr, acc[mt], 0, 0, 0);
            }
        }
    }
    __syncthreads();   // all sto (x-tile) reads done before overwrite
    const int orow = (l >> 4) * 4, ocol = l & 15;
    float bb = bias[wv * 16 + ocol];
    #pragma unroll
    for (int mt = 0; mt < 4; ++mt)
        #pragma unroll
        for (int j = 0; j < 4; ++j)
            sto[(mt * 16 + orow + j) * 136 + wv * 16 + ocol] =
                f2b(fmaxf(acc[mt][j] + bb, 0.0f));
    __syncthreads();
    store_tile_fp8(sto, n0, h8);
}

// ------- fused agg + conv2 + U/V: h2 in LDS; U -> fp8, V -> fp8 -------
__global__ __launch_bounds__(512) void k_aggconv2uv(const unsigned char* __restrict__ h8,
                                                    const int* __restrict__ rs,
                                                    const int* __restrict__ re,
                                                    const int* __restrict__ srcs,
                                                    const unsigned short* __restrict__ Wlb,
                                                    const unsigned short* __restrict__ Wrb,
                                                    const float* __restrict__ bias,
                                                    const unsigned short* __restrict__ Wm1b,
                                                    const float* __restrict__ bm1,
                                                    unsigned char* __restrict__ U8,
                                                    unsigned char* __restrict__ V8) {
    __shared__ unsigned short agt[64 * 136];
    __shared__ unsigned short sto[64 * 136];
    const int tid = threadIdx.x;
    const int n0 = blockIdx.x * 64;

    stage_tile_fp8in(h8, n0, sto);            // h1 root tile -> sto
    gather_mean64(h8, rs, re, srcs, n0, agt); // fp8 gather
    __syncthreads();                          // (a)

    const int wv = tid >> 6, l = tid & 63;
    const int lrow = l & 15, lk = (l >> 4) * 8;
    const int orow = (l >> 4) * 4, ocol = l & 15;

    // phase 1: h2 = relu(agg@W2l^T + b + h1@W2r^T)
    f32x4 acc[4] = {};
    #pragma unroll
    for (int p = 0; p < 2; ++p) {
        const unsigned short* W  = p ? Wrb : Wlb;
        const unsigned short* At = p ? sto : agt;
        #pragma unroll
        for (int ks = 0; ks < 4; ++ks) {
            bf16x8 bfr = *(const bf16x8*)&W[(size_t)(wv * 16 + lrow) * D + ks * 32 + lk];
            #pragma unroll
            for (int mt = 0; mt < 4; ++mt) {
                bf16x8 af = *(const bf16x8*)&At[(mt * 16 + lrow) * 136 + ks * 32 + lk];
                acc[mt] = __builtin_amdgcn_mfma_f32_16x16x32_bf16(af, bfr, acc[mt], 0, 0, 0);
            }
        }
    }
    __syncthreads();                          // (b) all agt/sto reads done
    {   // h2 epilogue -> agt
        float bb = bias[wv * 16 + ocol];
        #pragma unroll
        for (int mt = 0; mt < 4; ++mt)
            #pragma unroll
            for (int j = 0; j < 4; ++j)
                agt[(mt * 16 + orow + j) * 136 + wv * 16 + ocol] =
                    f2b(fmaxf(acc[mt][j] + bb, 0.0f));
    }
    __syncthreads();                          // (c) h2 tile complete in agt

    f32x4 aU[4] = {}, aV[4] = {};
    #pragma unroll
    for (int ks = 0; ks < 4; ++ks) {
        bf16x8 bu = *(const bf16x8*)&Wm1b[(size_t)(wv * 16 + lrow) * 256 + ks * 32 + lk];
        bf16x8 bv = *(const bf16x8*)&Wm1b[(size_t)(wv * 16 + lrow) * 256 + 128 + ks * 32 + lk];
        #pragma unroll
        for (int mt = 0; mt < 4; ++mt) {
            bf16x8 af = *(const bf16x8*)&agt[(mt * 16 + lrow) * 136 + ks * 32 + lk];
            aU[mt] = __builtin_amdgcn_mfma_f32_16x16x32_bf16(af, bu, aU[mt], 0, 0, 0);
            aV[mt] = __builtin_amdgcn_mfma_f32_16x16x32_bf16(af, bv, aV[mt], 0, 0, 0);
        }
    }
    {   // stage U -> sto (root-tile reads ended at (b))
        float bb = bm1[wv * 16 + ocol];
        #pragma unroll
        for (int mt = 0; mt < 4; ++mt)
            #pragma unroll
            for (int j = 0; j < 4; ++j)
                sto[(mt * 16 + orow + j) * 136 + wv * 16 + ocol] = f2b(aU[mt][j] + bb);
    }
    __syncthreads();                          // (d) U staged; all agt (h2) reads done
    store_tile_fp8(sto, n0, U8);              // U as fp8
    {   // stage V -> agt
        #pragma unroll
        for (int mt = 0; mt < 4; ++mt)
            #pragma unroll
            for (int j = 0; j < 4; ++j)
                agt[(mt * 16 + orow + j) * 136 + wv * 16 + ocol] = f2b(aV[mt][j]);
    }
    __syncthreads();                          // (e)
    store_tile_fp8(agt, n0, V8);              // V as fp8
}

// ---------------- edge finalize, dst-grouped, fp8 U and V ------------------
__global__ __launch_bounds__(256) void k_edge2(const unsigned char* __restrict__ U8,
                                               const unsigned char* __restrict__ V8,
                                               const int* __restrict__ rs,
                                               const int* __restrict__ re,
                                               const int* __restrict__ srcs,
                                               const int* __restrict__ eids,
                                               const float* __restrict__ wm2,
                                               const float* __restrict__ bm2,
                                               float* __restrict__ out) {
    int t = blockIdx.x * 256 + threadIdx.x;
    int g = t >> 4, q = t & 15;
    if (g >= NN) return;
    int b = rs[g], e = re[g];
    if (b == e) return;
    uint2 vv = *(const uint2*)&V8[(size_t)g * 128 + q * 8];
    float vf[8], wf[8];
    {
        f32x2 p0 = __builtin_amdgcn_cvt_pk_f32_fp8(vv.x, false);
        f32x2 p1 = __builtin_amdgcn_cvt_pk_f32_fp8(vv.x, true);
        f32x2 p2 = __builtin_amdgcn_cvt_pk_f32_fp8(vv.y, false);
        f32x2 p3 = __builtin_amdgcn_cvt_pk_f32_fp8(vv.y, true);
        vf[0] = p0.x; vf[1] = p0.y; vf[2] = p1.x; vf[3] = p1.y;
        vf[4] = p2.x; vf[5] = p2.y; vf[6] = p3.x; vf[7] = p3.y;
    }
    float4 w0 = *(const float4*)&wm2[q * 8];
    float4 w1 = *(const float4*)&wm2[q * 8 + 4];
    wf[0] = w0.x; wf[1] = w0.y; wf[2] = w0.z; wf[3] = w0.w;
    wf[4] = w1.x; wf[5] = w1.y; wf[6] = w1.z; wf[7] = w1.w;
    const float bb = bm2[0];

#define EDOT(p, u) {                                                   \
    f32x2 q0 = __builtin_amdgcn_cvt_pk_f32_fp8(u.x, false);            \
    f32x2 q1 = __builtin_amdgcn_cvt_pk_f32_fp8(u.x, true);             \
    f32x2 q2 = __builtin_amdgcn_cvt_pk_f32_fp8(u.y, false);            \
    f32x2 q3 = __builtin_amdgcn_cvt_pk_f32_fp8(u.y, true);             \
    p += fmaxf(q0.x + vf[0], 0.0f) * wf[0] + fmaxf(q0.y + vf[1], 0.0f) * wf[1] \
       + fmaxf(q1.x + vf[2], 0.0f) * wf[2] + fmaxf(q1.y + vf[3], 0.0f) * wf[3] \
       + fmaxf(q2.x + vf[4], 0.0f) * wf[4] + fmaxf(q2.y + vf[5], 0.0f) * wf[5] \
       + fmaxf(q3.x + vf[6], 0.0f) * wf[6] + fmaxf(q3.y + vf[7], 0.0f) * wf[7]; }

    int j = b;
    for (; j + 7 < e; j += 8) {
        uint2 u0 = *(const uint2*)&U8[(size_t)srcs[j]     * 128 + q * 8];
        uint2 u1 = *(const uint2*)&U8[(size_t)srcs[j + 1] * 128 + q * 8];
        uint2 u2 = *(const uint2*)&U8[(size_t)srcs[j + 2] * 128 + q * 8];
        uint2 u3 = *(const uint2*)&U8[(size_t)srcs[j + 3] * 128 + q * 8];
        uint2 u4 = *(const uint2*)&U8[(size_t)srcs[j + 4] * 128 + q * 8];
        uint2 u5 = *(const uint2*)&U8[(size_t)srcs[j + 5] * 128 + q * 8];
        uint2 u6 = *(const uint2*)&U8[(size_t)srcs[j + 6] * 128 + q * 8];
        uint2 u7 = *(const uint2*)&U8[(size_t)srcs[j + 7] * 128 + q * 8];
        float p0 = 0.f, p1 = 0.f, p2 = 0.f, p3 = 0.f;
        float p4 = 0.f, p5 = 0.f, p6 = 0.f, p7 = 0.f;
        EDOT(p0, u0); EDOT(p1, u1); EDOT(p2, u2); EDOT(p3, u3);
        EDOT(p4, u4); EDOT(p5, u5); EDOT(p6, u6); EDOT(p7, u7);
        #pragma unroll
        for (int off = 1; off < 16; off <<= 1) {
            p0 += __shfl_xor(p0, off); p1 += __shfl_xor(p1, off);
            p2 += __shfl_xor(p2, off); p3 += __shfl_xor(p3, off);
            p4 += __shfl_xor(p4, off); p5 += __shfl_xor(p5, off);
            p6 += __shfl_xor(p6, off); p7 += __shfl_xor(p7, off);
        }
        if (q == 0) {
            out[eids[j]]     = 1.0f / (1.0f + expf(-(p0 + bb)));
            out[eids[j + 1]] = 1.0f / (1.0f + expf(-(p1 + bb)));
            out[eids[j + 2]] = 1.0f / (1.0f + expf(-(p2 + bb)));
            out[eids[j + 3]] = 1.0f / (1.0f + expf(-(p3 + bb)));
            out[eids[j + 4]] = 1.0f / (1.0f + expf(-(p4 + bb)));
            out[eids[j + 5]] = 1.0f / (1.0f + expf(-(p5 + bb)));
            out[eids[j + 6]] = 1.0f / (1.0f + expf(-(p6 + bb)));
            out[eids[j + 7]] = 1.0f / (1.0f + expf(-(p7 + bb)));
        }
    }
    for (; j + 3 < e; j += 4) {
        uint2 u0 = *(const uint2*)&U8[(size_t)srcs[j]     * 128 + q * 8];
        uint2 u1 = *(const uint2*)&U8[(size_t)srcs[j + 1] * 128 + q * 8];
        uint2 u2 = *(const uint2*)&U8[(size_t)srcs[j + 2] * 128 + q * 8];
        uint2 u3 = *(const uint2*)&U8[(size_t)srcs[j + 3] * 128 + q * 8];
        float p0 = 0.f, p1 = 0.f, p2 = 0.f, p3 = 0.f;
        EDOT(p0, u0); EDOT(p1, u1); EDOT(p2, u2); EDOT(p3, u3);
        #pragma unroll
        for (int off = 1; off < 16; off <<= 1) {
            p0 += __shfl_xor(p0, off); p1 += __shfl_xor(p1, off);
            p2 += __shfl_xor(p2, off); p3 += __shfl_xor(p3, off);
        }
        if (q == 0) {
            out[eids[j]]     = 1.0f / (1.0f + expf(-(p0 + bb)));
            out[eids[j + 1]] = 1.0f / (1.0f + expf(-(p1 + bb)));
            out[eids[j + 2]] = 1.0f / (1.0f + expf(-(p2 + bb)));
            out[eids[j + 3]] = 1.0f / (1.0f + expf(-(p3 + bb)));
        }
    }
    for (; j < e; ++j) {
        uint2 u0 = *(const uint2*)&U8[(size_t)srcs[j] * 128 + q * 8];
        float p0 = 0.f;
        EDOT(p0, u0);
        #pragma unroll
        for (int off = 1; off < 16; off <<= 1) p0 += __shfl_xor(p0, off);
        if (q == 0) out[eids[j]] = 1.0f / (1.0f + expf(-(p0 + bb)));
    }
}

extern "C" void kernel_launch(void* const* d_in, const int* in_sizes, int n_in,
                              void* d_out, int out_size, void* d_ws, size_t ws_size,
                              hipStream_t stream) {
    const float* x   = (const float*)d_in[0];
    const int*   ei  = (const int*)d_in[1];
    const int*   src = ei;
    const int*   dst = ei + NE;
    const float* W1l = (const float*)d_in[2];
    const float* b1l = (const float*)d_in[3];
    const float* W1r = (const float*)d_in[4];
    const float* W2l = (const float*)d_in[5];
    const float* b2l = (const float*)d_in[6];
    const float* W2r = (const float*)d_in[7];
    const float* Wm1 = (const float*)d_in[8];
    const float* bm1 = (const float*)d_in[9];
    const float* Wm2 = (const float*)d_in[10];
    const float* bm2 = (const float*)d_in[11];
    float* out = (float*)d_out;

    char* ws = (char*)d_ws;
    int* rs   = (int*)(ws + OFF_RS);
    int* cnt  = (int*)(ws + OFF_CNT);
    int* cur  = (int*)(ws + OFF_CUR);    // row_end after scatter_idx
    int* bsum = (int*)(ws + OFF_BS);
    unsigned short* wb = (unsigned short*)(ws + OFF_WB);
    int* srcs = (int*)(ws + OFF_SRC);
    int* eids = (int*)(ws + OFF_EID);
    unsigned char*  V8 = (unsigned char*)(ws + OFF_V8);   // fp8 V
    unsigned char*  X8 = (unsigned char*)(ws + OFF_X8);   // fp8 x
    unsigned char*  H8 = (unsigned char*)(ws + OFF_H8);   // fp8 h1
    unsigned char*  U8 = (unsigned char*)(ws + OFF_U8);   // fp8 U

    unsigned short* W1lb = wb;
    unsigned short* W1rb = wb + 16384;
    unsigned short* W2lb = wb + 32768;
    unsigned short* W2rb = wb + 49152;
    unsigned short* Wm1b = wb + 65536;

    const int NB = 391;               // ceil(NN/256)
    const int NB64 = (NN + 63) / 64;  // 1563

    hipMemsetAsync(cnt, 0, NN * sizeof(int), stream);
    k_prep<<<12500 + 384 + 3125, 256, 0, stream>>>(x, (unsigned*)X8,
                                                   W1l, W1r, W2l, W2r, Wm1,
                                                   wb, dst, cnt);
    k_scan1<<<NB, 256, 0, stream>>>(cnt, bsum);
    k_scan2<<<1, 512, 0, stream>>>(bsum, NB);
    k_scan3<<<NB, 256, 0, stream>>>(cnt, bsum, rs, cur);
    k_scatter_idx<<<(NE + 255) / 256, 256, 0, stream>>>(src, dst, cur, srcs, eids);

    k_aggconv1<<<NB64, 512, 0, stream>>>(X8, rs, cur, srcs,
                                         W1lb, W1rb, b1l, H8);             // h1 -> H8
    k_aggconv2uv<<<NB64, 512, 0, stream>>>(H8, rs, cur, srcs,
                                           W2lb, W2rb, b2l, Wm1b, bm1,
                                           U8, V8);                        // U -> U8, V -> V8
    k_edge2<<<(NN * 16 + 255) / 256, 256, 0, stream>>>(U8, V8, rs, cur, srcs, eids,
                                                       Wm2, bm2, out);
}

// Round 15
// 257.063 us; speedup vs baseline: 1.1539x; 1.0105x over previous
//
#include <hip/hip_runtime.h>
#include <math.h>

#define NN 100000
#define NE 800000
#define D 128

typedef __attribute__((ext_vector_type(8))) short bf16x8;
typedef __attribute__((ext_vector_type(8))) unsigned short u16x8;
typedef __attribute__((ext_vector_type(4))) float f32x4;
typedef __attribute__((ext_vector_type(2))) float f32x2;

// ---- workspace layout (bytes) ----
constexpr size_t OFF_RS  = 0;                         // int[NN+1]
constexpr size_t OFF_CNT = 512 * 1024;                // int[NN] histogram
constexpr size_t OFF_CUR = 1024 * 1024;               // int[NN] cursor -> row_end
constexpr size_t OFF_BS  = 1536 * 1024;               // int[512] block sums
constexpr size_t OFF_WB  = 1552 * 1024;               // bf16 weights (98304 elems)
constexpr size_t OFF_SE  = 2 * 1024 * 1024;           // int2[NE] {src, eid}
constexpr size_t OFF_V8  = 10 * 1024 * 1024;          // fp8 V   [NN*128]
constexpr size_t OFF_X8  = OFF_V8 + 13 * 1024 * 1024; // fp8 x   [NN*128]
constexpr size_t OFF_H8  = OFF_X8 + 13 * 1024 * 1024; // fp8 h1  [NN*128]
constexpr size_t OFF_U8  = OFF_H8 + 13 * 1024 * 1024; // fp8 U   [NN*128]

__device__ __forceinline__ unsigned short f2b(float f) {
    unsigned u = __builtin_bit_cast(unsigned, f);
    return (unsigned short)((u + 0x7FFFu + ((u >> 16) & 1u)) >> 16);
}
__device__ __forceinline__ float b2f(unsigned short h) {
    unsigned u = ((unsigned)h) << 16;
    return __builtin_bit_cast(float, u);
}
// packed f32x2 -> 2x bf16 in one instr (no builtin on gfx950; RNE like f2b)
__device__ __forceinline__ unsigned pk_bf16(float lo, float hi) {
    unsigned r;
    asm("v_cvt_pk_bf16_f32 %0, %1, %2" : "=v"(r) : "v"(lo), "v"(hi));
    return r;
}
__device__ __forceinline__ unsigned short f2b_fast(float f) {
    return (unsigned short)pk_bf16(f, f);
}
__device__ __forceinline__ f32x2 relu2(f32x2 a) {
    f32x2 r; r.x = fmaxf(a.x, 0.f); r.y = fmaxf(a.y, 0.f); return r;
}

// ------------- fused prep: x->fp8 | weights->bf16 | degree histogram --------
__global__ __launch_bounds__(256) void k_prep(const float* __restrict__ x,
                                              unsigned* __restrict__ x8w,
                                              const float* __restrict__ W1l,
                                              const float* __restrict__ W1r,
                                              const float* __restrict__ W2l,
                                              const float* __restrict__ W2r,
                                              const float* __restrict__ Wm1,
                                              unsigned short* __restrict__ wb,
                                              const int* __restrict__ dst,
                                              int* __restrict__ cnt) {
    int bid = blockIdx.x, tid = threadIdx.x;
    if (bid < 12500) {                       // x conversion, float4 granules
        int i = bid * 256 + tid;             // 3,200,000 = NN*D/4 exactly
        float4 v = *(const float4*)&x[(size_t)i * 4];
        unsigned p = __builtin_amdgcn_cvt_pk_fp8_f32(v.x, v.y, 0u, false);
        p = __builtin_amdgcn_cvt_pk_fp8_f32(v.z, v.w, p, true);
        x8w[i] = p;
    } else if (bid < 12884) {                // weights: 98304 elems
        int i = (bid - 12500) * 256 + tid;
        float v;
        if (i < 16384) v = W1l[i];
        else if (i < 32768) v = W1r[i - 16384];
        else if (i < 49152) v = W2l[i - 32768];
        else if (i < 65536) v = W2r[i - 49152];
        else v = Wm1[i - 65536];
        wb[i] = f2b(v);
    } else {                                 // degree histogram
        int e = (bid - 12884) * 256 + tid;
        atomicAdd(&cnt[dst[e]], 1);
    }
}

// ---------------- CSR scan chain ----------------
__global__ __launch_bounds__(256) void k_scan1(const int* __restrict__ cnt,
                                               int* __restrict__ bsum) {
    int i = blockIdx.x * 256 + threadIdx.x;
    int v = (i < NN) ? cnt[i] : 0;
    #pragma unroll
    for (int o = 1; o < 64; o <<= 1) v += __shfl_xor(v, o);
    __shared__ int wsum[4];
    if ((threadIdx.x & 63) == 0) wsum[threadIdx.x >> 6] = v;
    __syncthreads();
    if (threadIdx.x == 0) bsum[blockIdx.x] = wsum[0] + wsum[1] + wsum[2] + wsum[3];
}

__global__ __launch_bounds__(512) void k_scan2(int* __restrict__ bsum, int nb) {
    __shared__ int s[512];
    int t = threadIdx.x;
    int v = (t < nb) ? bsum[t] : 0;
    s[t] = v;
    __syncthreads();
    for (int o = 1; o < 512; o <<= 1) {
        int u = (t >= o) ? s[t - o] : 0;
        __syncthreads();
        s[t] += u;
        __syncthreads();
    }
    if (t < nb) bsum[t] = s[t] - v;   // exclusive
}

__global__ __launch_bounds__(256) void k_scan3(const int* __restrict__ cnt,
                                               const int* __restrict__ bsum,
                                               int* __restrict__ rs,
                                               int* __restrict__ cur) {
    __shared__ int s[256];
    int t = threadIdx.x;
    int i = blockIdx.x * 256 + t;
    int v = (i < NN) ? cnt[i] : 0;
    s[t] = v;
    __syncthreads();
    for (int o = 1; o < 256; o <<= 1) {
        int u = (t >= o) ? s[t - o] : 0;
        __syncthreads();
        s[t] += u;
        __syncthreads();
    }
    int ex = s[t] - v + bsum[blockIdx.x];
    if (i < NN) { rs[i] = ex; cur[i] = ex; }
    if (i == NN - 1) rs[NN] = ex + v;
}

__global__ __launch_bounds__(256) void k_scatter_idx(const int* __restrict__ src,
                                                     const int* __restrict__ dst,
                                                     int* __restrict__ cur,
                                                     int2* __restrict__ se) {
    int e = blockIdx.x * 256 + threadIdx.x;
    if (e < NE) {
        int pos = atomicAdd(&cur[dst[e]], 1);
        se[pos] = make_int2(src[e], e);
    }
}

// ---- gather-mean (fp8 rows) for 64 nodes into LDS tile [64][136] bf16 -----
// 16 lanes/node, 8B per lane per edge, 8-deep unrolled; packed f32x2 accum.
#define UNPK8v(acc, u) {                                              \
    acc[0] += __builtin_amdgcn_cvt_pk_f32_fp8(u.x, false);            \
    acc[1] += __builtin_amdgcn_cvt_pk_f32_fp8(u.x, true);             \
    acc[2] += __builtin_amdgcn_cvt_pk_f32_fp8(u.y, false);            \
    acc[3] += __builtin_amdgcn_cvt_pk_f32_fp8(u.y, true); }

__device__ __forceinline__ void gather_mean64(const unsigned char* __restrict__ feat8,
                                              const int* __restrict__ rs,
                                              const int* __restrict__ re,
                                              const int2* __restrict__ se,
                                              int n0, unsigned short* agt) {
    const int tid = threadIdx.x;
    const int g = tid >> 4, q = tid & 15;   // g in 0..31
    #pragma unroll
    for (int half = 0; half < 2; ++half) {
        int r = half * 32 + g;
        int n = n0 + r;
        if (n > NN - 1) n = NN - 1;          // tail clamp (NN%64==32)
        int b = rs[n], e = re[n];
        f32x2 a0[4] = {}, a1[4] = {}, a2[4] = {}, a3[4] = {};
        int j = b;
        for (; j + 7 < e; j += 8) {
            uint2 v0 = *(const uint2*)&feat8[(size_t)se[j].x     * 128 + q * 8];
            uint2 v1 = *(const uint2*)&feat8[(size_t)se[j + 1].x * 128 + q * 8];
            uint2 v2 = *(const uint2*)&feat8[(size_t)se[j + 2].x * 128 + q * 8];
            uint2 v3 = *(const uint2*)&feat8[(size_t)se[j + 3].x * 128 + q * 8];
            uint2 v4 = *(const uint2*)&feat8[(size_t)se[j + 4].x * 128 + q * 8];
            uint2 v5 = *(const uint2*)&feat8[(size_t)se[j + 5].x * 128 + q * 8];
            uint2 v6 = *(const uint2*)&feat8[(size_t)se[j + 6].x * 128 + q * 8];
            uint2 v7 = *(const uint2*)&feat8[(size_t)se[j + 7].x * 128 + q * 8];
            UNPK8v(a0, v0); UNPK8v(a1, v1); UNPK8v(a2, v2); UNPK8v(a3, v3);
            UNPK8v(a0, v4); UNPK8v(a1, v5); UNPK8v(a2, v6); UNPK8v(a3, v7);
        }
        for (; j + 3 < e; j += 4) {
            uint2 v0 = *(const uint2*)&feat8[(size_t)se[j].x     * 128 + q * 8];
            uint2 v1 = *(const uint2*)&feat8[(size_t)se[j + 1].x * 128 + q * 8];
            uint2 v2 = *(const uint2*)&feat8[(size_t)se[j + 2].x * 128 + q * 8];
            uint2 v3 = *(const uint2*)&feat8[(size_t)se[j + 3].x * 128 + q * 8];
            UNPK8v(a0, v0); UNPK8v(a1, v1); UNPK8v(a2, v2); UNPK8v(a3, v3);
        }
        for (; j < e; ++j) {
            uint2 v0 = *(const uint2*)&feat8[(size_t)se[j].x * 128 + q * 8];
            UNPK8v(a0, v0);
        }
        float inv = 1.0f / fmaxf((float)(e - b), 1.0f);
        f32x2 iv; iv.x = inv; iv.y = inv;
        f32x2 s0 = (a0[0] + a1[0] + a2[0] + a3[0]) * iv;
        f32x2 s1 = (a0[1] + a1[1] + a2[1] + a3[1]) * iv;
        f32x2 s2 = (a0[2] + a1[2] + a2[2] + a3[2]) * iv;
        f32x2 s3 = (a0[3] + a1[3] + a2[3] + a3[3]) * iv;
        uint4 o;
        o.x = pk_bf16(s0.x, s0.y);
        o.y = pk_bf16(s1.x, s1.y);
        o.z = pk_bf16(s2.x, s2.y);
        o.w = pk_bf16(s3.x, s3.y);
        *(uint4*)&agt[r * 136 + q * 8] = o;
    }
}

// stage 64 fp8 rows -> LDS tile [64][136] bf16 (coalesced 16B/lane, clamped)
__device__ __forceinline__ void stage_tile_fp8in(const unsigned char* __restrict__ src8,
                                                 int n0, unsigned short* t) {
    const int tid = threadIdx.x;          // 512 thr x 16B = whole tile
    int r = tid >> 3, q = tid & 7;
    int gr = n0 + r;
    if (gr > NN - 1) gr = NN - 1;
    uint4 v = *(const uint4*)&src8[(size_t)gr * 128 + q * 16];
    f32x2 p0 = __builtin_amdgcn_cvt_pk_f32_fp8(v.x, false);
    f32x2 p1 = __builtin_amdgcn_cvt_pk_f32_fp8(v.x, true);
    f32x2 p2 = __builtin_amdgcn_cvt_pk_f32_fp8(v.y, false);
    f32x2 p3 = __builtin_amdgcn_cvt_pk_f32_fp8(v.y, true);
    uint4 o0;
    o0.x = pk_bf16(p0.x, p0.y); o0.y = pk_bf16(p1.x, p1.y);
    o0.z = pk_bf16(p2.x, p2.y); o0.w = pk_bf16(p3.x, p3.y);
    f32x2 p4 = __builtin_amdgcn_cvt_pk_f32_fp8(v.z, false);
    f32x2 p5 = __builtin_amdgcn_cvt_pk_f32_fp8(v.z, true);
    f32x2 p6 = __builtin_amdgcn_cvt_pk_f32_fp8(v.w, false);
    f32x2 p7 = __builtin_amdgcn_cvt_pk_f32_fp8(v.w, true);
    uint4 o1;
    o1.x = pk_bf16(p4.x, p4.y); o1.y = pk_bf16(p5.x, p5.y);
    o1.z = pk_bf16(p6.x, p6.y); o1.w = pk_bf16(p7.x, p7.y);
    *(uint4*)&t[r * 136 + q * 16]     = o0;
    *(uint4*)&t[r * 136 + q * 16 + 8] = o1;
}

// store LDS bf16 tile -> global fp8 (coalesced 4B words, guarded)
__device__ __forceinline__ void store_tile_fp8(const unsigned short* t,
                                               int n0, unsigned char* __restrict__ dst8) {
    const int tid = threadIdx.x;
    #pragma unroll
    for (int it = 0; it < 4; ++it) {
        int w = it * 512 + tid;          // word 0..2047
        int r = w >> 5, c4 = (w & 31) * 4;
        int gr = n0 + r;
        if (gr < NN) {
            unsigned p = __builtin_amdgcn_cvt_pk_fp8_f32(
                b2f(t[r * 136 + c4 + 0]), b2f(t[r * 136 + c4 + 1]), 0u, false);
            p = __builtin_amdgcn_cvt_pk_fp8_f32(
                b2f(t[r * 136 + c4 + 2]), b2f(t[r * 136 + c4 + 3]), p, true);
            *(unsigned*)&dst8[(size_t)gr * 128 + c4] = p;
        }
    }
}

// ---------------- fused agg + conv1: h1 = relu(mean@W1l^T + b + x@W1r^T) ----
__global__ __launch_bounds__(512) void k_aggconv1(const unsigned char* __restrict__ x8,
                                                  const int* __restrict__ rs,
                                                  const int* __restrict__ re,
                                                  const int2* __restrict__ se,
                                                  const unsigned short* __restrict__ Wlb,
                                                  const unsigned short* __restrict__ Wrb,
                                                  const float* __restrict__ bias,
                                                  unsigned char* __restrict__ h8) {
    __shared__ unsigned short agt[64 * 136];
    __shared__ unsigned short sto[64 * 136];
    const int tid = threadIdx.x;
    const int n0 = blockIdx.x * 64;

    stage_tile_fp8in(x8, n0, sto);
    gather_mean64(x8, rs, re, se, n0, agt);
    __syncthreads();

    const int wv = tid >> 6, l = tid & 63;
    const int lrow = l & 15, lk = (l >> 4) * 8;
    f32x4 acc[4] = {};
    #pragma unroll
    for (int p = 0; p < 2; ++p) {
        const unsigned short* W  = p ? Wrb : Wlb;
        const unsigned short* At = p ? sto : agt;
        #pragma unroll
        for (int ks = 0; ks < 4; ++ks) {
            bf16x8 bfr = *(const bf16x8*)&W[(size_t)(wv * 16 + lrow) * D + ks * 32 + lk];
            #pragma unroll
            for (int mt = 0; mt < 4; ++mt) {
                bf16x8 af = *(const bf16x8*)&At[(mt * 16 + lrow) * 136 + ks * 32 + lk];
                acc[mt] = __builtin_amdgcn_mfma_f32_16x16x32_bf16(af, bfr, acc[mt], 0, 0, 0);
            }
        }
    }
    __syncthreads();   // all sto (x-tile) reads done before overwrite
    const int orow = (l >> 4) * 4, ocol = l & 15;
    float bb = bias[wv * 16 + ocol];
    #pragma unroll
    for (int mt = 0; mt < 4; ++mt)
        #pragma unroll
        for (int j = 0; j < 4; ++j)
            sto[(mt * 16 + orow + j) * 136 + wv * 16 + ocol] =
                f2b_fast(fmaxf(acc[mt][j] + bb, 0.0f));
    __syncthreads();
    store_tile_fp8(sto, n0, h8);
}

// ------- fused agg + conv2 + U/V: h2 in LDS; U -> fp8, V -> fp8 -------
__global__ __launch_bounds__(512) void k_aggconv2uv(const unsigned char* __restrict__ h8,
                                                    const int* __restrict__ rs,
                                                    const int* __restrict__ re,
                                                    const int2* __restrict__ se,
                                                    const unsigned short* __restrict__ Wlb,
                                                    const unsigned short* __restrict__ Wrb,
                                                    const float* __restrict__ bias,
                                                    const unsigned short* __restrict__ Wm1b,
                                                    const float* __restrict__ bm1,
                                                    unsigned char* __restrict__ U8,
                                                    unsigned char* __restrict__ V8) {
    __shared__ unsigned short agt[64 * 136];
    __shared__ unsigned short sto[64 * 136];
    const int tid = threadIdx.x;
    const int n0 = blockIdx.x * 64;

    stage_tile_fp8in(h8, n0, sto);            // h1 root tile -> sto
    gather_mean64(h8, rs, re, se, n0, agt);   // fp8 gather
    __syncthreads();                          // (a)

    const int wv = tid >> 6, l = tid & 63;
    const int lrow = l & 15, lk = (l >> 4) * 8;
    const int orow = (l >> 4) * 4, ocol = l & 15;

    // phase 1: h2 = relu(agg@W2l^T + b + h1@W2r^T)
    f32x4 acc[4] = {};
    #pragma unroll
    for (int p = 0; p < 2; ++p) {
        const unsigned short* W  = p ? Wrb : Wlb;
        const unsigned short* At = p ? sto : agt;
        #pragma unroll
        for (int ks = 0; ks < 4; ++ks) {
            bf16x8 bfr = *(const bf16x8*)&W[(size_t)(wv * 16 + lrow) * D + ks * 32 + lk];
            #pragma unroll
            for (int mt = 0; mt < 4; ++mt) {
                bf16x8 af = *(const bf16x8*)&At[(mt * 16 + lrow) * 136 + ks * 32 + lk];
                acc[mt] = __builtin_amdgcn_mfma_f32_16x16x32_bf16(af, bfr, acc[mt], 0, 0, 0);
            }
        }
    }
    __syncthreads();                          // (b) all agt/sto reads done
    {   // h2 epilogue -> agt
        float bb = bias[wv * 16 + ocol];
        #pragma unroll
        for (int mt = 0; mt < 4; ++mt)
            #pragma unroll
            for (int j = 0; j < 4; ++j)
                agt[(mt * 16 + orow + j) * 136 + wv * 16 + ocol] =
                    f2b_fast(fmaxf(acc[mt][j] + bb, 0.0f));
    }
    __syncthreads();                          // (c) h2 tile complete in agt

    f32x4 aU[4] = {}, aV[4] = {};
    #pragma unroll
    for (int ks = 0; ks < 4; ++ks) {
        bf16x8 bu = *(const bf16x8*)&Wm1b[(size_t)(wv * 16 + lrow) * 256 + ks * 32 + lk];
        bf16x8 bv = *(const bf16x8*)&Wm1b[(size_t)(wv * 16 + lrow) * 256 + 128 + ks * 32 + lk];
        #pragma unroll
        for (int mt = 0; mt < 4; ++mt) {
            bf16x8 af = *(const bf16x8*)&agt[(mt * 16 + lrow) * 136 + ks * 32 + lk];
            aU[mt] = __builtin_amdgcn_mfma_f32_16x16x32_bf16(af, bu, aU[mt], 0, 0, 0);
            aV[mt] = __builtin_amdgcn_mfma_f32_16x16x32_bf16(af, bv, aV[mt], 0, 0, 0);
        }
    }
    {   // stage U -> sto (root-tile reads ended at (b))
        float bb = bm1[wv * 16 + ocol];
        #pragma unroll
        for (int mt = 0; mt < 4; ++mt)
            #pragma unroll
            for (int j = 0; j < 4; ++j)
                sto[(mt * 16 + orow + j) * 136 + wv * 16 + ocol] = f2b_fast(aU[mt][j] + bb);
    }
    __syncthreads();                          // (d) U staged; all agt (h2) reads done
    store_tile_fp8(sto, n0, U8);              // U as fp8
    {   // stage V -> agt
        #pragma unroll
        for (int mt = 0; mt < 4; ++mt)
            #pragma unroll
            for (int j = 0; j < 4; ++j)
                agt[(mt * 16 + orow + j) * 136 + wv * 16 + ocol] = f2b_fast(aV[mt][j]);
    }
    __syncthreads();                          // (e)
    store_tile_fp8(agt, n0, V8);              // V as fp8
}

// ---------------- edge finalize, dst-grouped, fp8 U and V, packed f32 ------
__global__ __launch_bounds__(256) void k_edge2(const unsigned char* __restrict__ U8,
                                               const unsigned char* __restrict__ V8,
                                               const int* __restrict__ rs,
                                               const int* __restrict__ re,
                                               const int2* __restrict__ se,
                                               const float* __restrict__ wm2,
                                               const float* __restrict__ bm2,
                                               float* __restrict__ out) {
    int t = blockIdx.x * 256 + threadIdx.x;
    int g = t >> 4, q = t & 15;
    if (g >= NN) return;
    int b = rs[g], e = re[g];
    if (b == e) return;
    uint2 vv = *(const uint2*)&V8[(size_t)g * 128 + q * 8];
    f32x2 vf2[4];
    vf2[0] = __builtin_amdgcn_cvt_pk_f32_fp8(vv.x, false);
    vf2[1] = __builtin_amdgcn_cvt_pk_f32_fp8(vv.x, true);
    vf2[2] = __builtin_amdgcn_cvt_pk_f32_fp8(vv.y, false);
    vf2[3] = __builtin_amdgcn_cvt_pk_f32_fp8(vv.y, true);
    float4 w0 = *(const float4*)&wm2[q * 8];
    float4 w1 = *(const float4*)&wm2[q * 8 + 4];
    f32x2 wf2[4];
    wf2[0].x = w0.x; wf2[0].y = w0.y; wf2[1].x = w0.z; wf2[1].y = w0.w;
    wf2[2].x = w1.x; wf2[2].y = w1.y; wf2[3].x = w1.z; wf2[3].y = w1.w;
    const float bb = bm2[0];

#define EDOTv(p2, u) {                                                   \
    f32x2 t0 = relu2(__builtin_amdgcn_cvt_pk_f32_fp8(u.x, false) + vf2[0]); \
    f32x2 t1 = relu2(__builtin_amdgcn_cvt_pk_f32_fp8(u.x, true)  + vf2[1]); \
    f32x2 t2 = relu2(__builtin_amdgcn_cvt_pk_f32_fp8(u.y, false) + vf2[2]); \
    f32x2 t3 = relu2(__builtin_amdgcn_cvt_pk_f32_fp8(u.y, true)  + vf2[3]); \
    p2 += t0 * wf2[0] + t1 * wf2[1] + t2 * wf2[2] + t3 * wf2[3]; }

    int j = b;
    for (; j + 7 < e; j += 8) {
        int2 s0 = se[j],     s1 = se[j + 1], s2 = se[j + 2], s3 = se[j + 3];
        int2 s4 = se[j + 4], s5 = se[j + 5], s6 = se[j + 6], s7 = se[j + 7];
        uint2 u0 = *(const uint2*)&U8[(size_t)s0.x * 128 + q * 8];
        uint2 u1 = *(const uint2*)&U8[(size_t)s1.x * 128 + q * 8];
        uint2 u2 = *(const uint2*)&U8[(size_t)s2.x * 128 + q * 8];
        uint2 u3 = *(const uint2*)&U8[(size_t)s3.x * 128 + q * 8];
        uint2 u4 = *(const uint2*)&U8[(size_t)s4.x * 128 + q * 8];
        uint2 u5 = *(const uint2*)&U8[(size_t)s5.x * 128 + q * 8];
        uint2 u6 = *(const uint2*)&U8[(size_t)s6.x * 128 + q * 8];
        uint2 u7 = *(const uint2*)&U8[(size_t)s7.x * 128 + q * 8];
        f32x2 q0 = {}, q1 = {}, q2 = {}, q3 = {}, q4 = {}, q5 = {}, q6 = {}, q7 = {};
        EDOTv(q0, u0); EDOTv(q1, u1); EDOTv(q2, u2); EDOTv(q3, u3);
        EDOTv(q4, u4); EDOTv(q5, u5); EDOTv(q6, u6); EDOTv(q7, u7);
        float p0 = q0.x + q0.y, p1 = q1.x + q1.y, p2 = q2.x + q2.y, p3 = q3.x + q3.y;
        float p4 = q4.x + q4.y, p5 = q5.x + q5.y, p6 = q6.x + q6.y, p7 = q7.x + q7.y;
        #pragma unroll
        for (int off = 1; off < 16; off <<= 1) {
            p0 += __shfl_xor(p0, off); p1 += __shfl_xor(p1, off);
            p2 += __shfl_xor(p2, off); p3 += __shfl_xor(p3, off);
            p4 += __shfl_xor(p4, off); p5 += __shfl_xor(p5, off);
            p6 += __shfl_xor(p6, off); p7 += __shfl_xor(p7, off);
        }
        if (q == 0) {
            out[s0.y] = 1.0f / (1.0f + expf(-(p0 + bb)));
            out[s1.y] = 1.0f / (1.0f + expf(-(p1 + bb)));
            out[s2.y] = 1.0f / (1.0f + expf(-(p2 + bb)));
            out[s3.y] = 1.0f / (1.0f + expf(-(p3 + bb)));
            out[s4.y] = 1.0f / (1.0f + expf(-(p4 + bb)));
            out[s5.y] = 1.0f / (1.0f + expf(-(p5 + bb)));
            out[s6.y] = 1.0f / (1.0f + expf(-(p6 + bb)));
            out[s7.y] = 1.0f / (1.0f + expf(-(p7 + bb)));
        }
    }
    for (; j + 3 < e; j += 4) {
        int2 s0 = se[j], s1 = se[j + 1], s2 = se[j + 2], s3 = se[j + 3];
        uint2 u0 = *(const uint2*)&U8[(size_t)s0.x * 128 + q * 8];
        uint2 u1 = *(const uint2*)&U8[(size_t)s1.x * 128 + q * 8];
        uint2 u2 = *(const uint2*)&U8[(size_t)s2.x * 128 + q * 8];
        uint2 u3 = *(const uint2*)&U8[(size_t)s3.x * 128 + q * 8];
        f32x2 q0 = {}, q1 = {}, q2 = {}, q3 = {};
        EDOTv(q0, u0); EDOTv(q1, u1); EDOTv(q2, u2); EDOTv(q3, u3);
        float p0 = q0.x + q0.y, p1 = q1.x + q1.y, p2 = q2.x + q2.y, p3 = q3.x + q3.y;
        #pragma unroll
        for (int off = 1; off < 16; off <<= 1) {
            p0 += __shfl_xor(p0, off); p1 += __shfl_xor(p1, off);
            p2 += __shfl_xor(p2, off); p3 += __shfl_xor(p3, off);
        }
        if (q == 0) {
            out[s0.y] = 1.0f / (1.0f + expf(-(p0 + bb)));
            out[s1.y] = 1.0f / (1.0f + expf(-(p1 + bb)));
            out[s2.y] = 1.0f / (1.0f + expf(-(p2 + bb)));
            out[s3.y] = 1.0f / (1.0f + expf(-(p3 + bb)));
        }
    }
    for (; j < e; ++j) {
        int2 s0 = se[j];
        uint2 u0 = *(const uint2*)&U8[(size_t)s0.x * 128 + q * 8];
        f32x2 q0 = {};
        EDOTv(q0, u0);
        float p0 = q0.x + q0.y;
        #pragma unroll
        for (int off = 1; off < 16; off <<= 1) p0 += __shfl_xor(p0, off);
        if (q == 0) out[s0.y] = 1.0f / (1.0f + expf(-(p0 + bb)));
    }
}

extern "C" void kernel_launch(void* const* d_in, const int* in_sizes, int n_in,
                              void* d_out, int out_size, void* d_ws, size_t ws_size,
                              hipStream_t stream) {
    const float* x   = (const float*)d_in[0];
    const int*   ei  = (const int*)d_in[1];
    const int*   src = ei;
    const int*   dst = ei + NE;
    const float* W1l = (const float*)d_in[2];
    const float* b1l = (const float*)d_in[3];
    const float* W1r = (const float*)d_in[4];
    const float* W2l = (const float*)d_in[5];
    const float* b2l = (const float*)d_in[6];
    const float* W2r = (const float*)d_in[7];
    const float* Wm1 = (const float*)d_in[8];
    const float* bm1 = (const float*)d_in[9];
    const float* Wm2 = (const float*)d_in[10];
    const float* bm2 = (const float*)d_in[11];
    float* out = (float*)d_out;

    char* ws = (char*)d_ws;
    int* rs   = (int*)(ws + OFF_RS);
    int* cnt  = (int*)(ws + OFF_CNT);
    int* cur  = (int*)(ws + OFF_CUR);    // row_end after scatter_idx
    int* bsum = (int*)(ws + OFF_BS);
    unsigned short* wb = (unsigned short*)(ws + OFF_WB);
    int2* se  = (int2*)(ws + OFF_SE);
    unsigned char*  V8 = (unsigned char*)(ws + OFF_V8);   // fp8 V
    unsigned char*  X8 = (unsigned char*)(ws + OFF_X8);   // fp8 x
    unsigned char*  H8 = (unsigned char*)(ws + OFF_H8);   // fp8 h1
    unsigned char*  U8 = (unsigned char*)(ws + OFF_U8);   // fp8 U

    unsigned short* W1lb = wb;
    unsigned short* W1rb = wb + 16384;
    unsigned short* W2lb = wb + 32768;
    unsigned short* W2rb = wb + 49152;
    unsigned short* Wm1b = wb + 65536;

    const int NB = 391;               // ceil(NN/256)
    const int NB64 = (NN + 63) / 64;  // 1563

    hipMemsetAsync(cnt, 0, NN * sizeof(int), stream);
    k_prep<<<12500 + 384 + 3125, 256, 0, stream>>>(x, (unsigned*)X8,
                                                   W1l, W1r, W2l, W2r, Wm1,
                                                   wb, dst, cnt);
    k_scan1<<<NB, 256, 0, stream>>>(cnt, bsum);
    k_scan2<<<1, 512, 0, stream>>>(bsum, NB);
    k_scan3<<<NB, 256, 0, stream>>>(cnt, bsum, rs, cur);
    k_scatter_idx<<<(NE + 255) / 256, 256, 0, stream>>>(src, dst, cur, se);

    k_aggconv1<<<NB64, 512, 0, stream>>>(X8, rs, cur, se,
                                         W1lb, W1rb, b1l, H8);             // h1 -> H8
    k_aggconv2uv<<<NB64, 512, 0, stream>>>(H8, rs, cur, se,
                                           W2lb, W2rb, b2l, Wm1b, bm1,
                                           U8, V8);                        // U -> U8, V -> V8
    k_edge2<<<(NN * 16 + 255) / 256, 256, 0, stream>>>(U8, V8, rs, cur, se,
                                                       Wm2, bm2, out);
}